// Round 1
// baseline (4766.590 us; speedup 1.0000x reference)
//
#include <hip/hip_runtime.h>
#include <cstdint>
#include <cstddef>

// Problem constants
#define T_  256
#define S_  128
#define B_  32
#define H_  1024
#define NH_ 16
#define D_  64
#define F_  4096
#define TB_ (T_*B_)   // 8192
#define SB_ (S_*B_)   // 4096

typedef unsigned short u16;
typedef unsigned int   u32;
typedef __attribute__((ext_vector_type(8))) short s16x8;   // 8 bf16 (4 VGPRs)
typedef __attribute__((ext_vector_type(4))) float f32x4;

static __device__ __forceinline__ float b2f(u16 u) {
  union { u32 i; float f; } cv; cv.i = ((u32)u) << 16; return cv.f;
}
static __device__ __forceinline__ u16 f2b(float f) {
  union { float f; u32 i; } cv; cv.f = f;
  u32 u = cv.i;
  u32 r = (u + 0x7fffu + ((u >> 16) & 1u)) >> 16;   // RNE
  return (u16)r;
}
static __device__ __forceinline__ float sigm(float x) {
  return 1.0f / (1.0f + __expf(-x));
}

// ---------------- cast fp32 -> bf16 (vectorized x4) ----------------
__global__ void cast_bf16(const float* __restrict__ in, u16* __restrict__ out, int n4) {
  int i = blockIdx.x * 256 + threadIdx.x;
  if (i < n4) {
    float4 v = reinterpret_cast<const float4*>(in)[i];
    ushort4 o;
    o.x = f2b(v.x); o.y = f2b(v.y); o.z = f2b(v.z); o.w = f2b(v.w);
    reinterpret_cast<ushort4*>(out)[i] = o;
  }
}

// ---------------- transpose + cast: in fp32 [R,C] -> out bf16 [C,R] ----------------
__global__ void transpose_cast(const float* __restrict__ in, u16* __restrict__ out,
                               int R, int C) {
  __shared__ float tile[32][33];
  int c0 = blockIdx.x * 32, r0 = blockIdx.y * 32;
  int tx = threadIdx.x, ty = threadIdx.y;
  #pragma unroll
  for (int k = 0; k < 32; k += 8)
    tile[ty + k][tx] = in[(size_t)(r0 + ty + k) * C + c0 + tx];
  __syncthreads();
  #pragma unroll
  for (int k = 0; k < 32; k += 8)
    out[(size_t)(c0 + ty + k) * R + r0 + tx] = f2b(tile[tx][ty + k]);
}

// ---------------- GEMM: Out[M,N] = act((A[M,K] @ Bt[N,K]^T + bias) * scale) ----------------
// bf16 in, bf16 out (fp32 accum). 128x128 block tile, 4 waves 2x2, 16x16x32 MFMA.
__global__ __launch_bounds__(256) void gemm_bt(
    const u16* __restrict__ A, const u16* __restrict__ Bt,
    u16* __restrict__ Out, const float* __restrict__ bias,
    int Kdim, int ostride, float scale, int relu)
{
  const int LDT = 40;  // 32 + 8 pad: breaks pow2 bank stride, keeps 16B alignment
  __shared__ u16 As[128 * 40];
  __shared__ u16 Bs[128 * 40];
  const int tid  = threadIdx.x;
  const int wave = tid >> 6, lane = tid & 63;
  const int quad = lane >> 4, l16 = lane & 15;
  const int bm = blockIdx.y << 7, bn = blockIdx.x << 7;
  const int wm = (wave & 1) << 6, wn = (wave >> 1) << 6;
  f32x4 acc[4][4] = {};

  const int sr = tid >> 2;          // staging row 0..63 (two passes cover 128)
  const int sc = (tid & 3) * 8;     // staging col in elems

  for (int k0 = 0; k0 < Kdim; k0 += 32) {
    *(uint4*)&As[sr * LDT + sc]        = *(const uint4*)&A[(size_t)(bm + sr) * Kdim + k0 + sc];
    *(uint4*)&As[(64 + sr) * LDT + sc] = *(const uint4*)&A[(size_t)(bm + 64 + sr) * Kdim + k0 + sc];
    *(uint4*)&Bs[sr * LDT + sc]        = *(const uint4*)&Bt[(size_t)(bn + sr) * Kdim + k0 + sc];
    *(uint4*)&Bs[(64 + sr) * LDT + sc] = *(const uint4*)&Bt[(size_t)(bn + 64 + sr) * Kdim + k0 + sc];
    __syncthreads();
    s16x8 af[4], bf[4];
    #pragma unroll
    for (int mt = 0; mt < 4; mt++)
      af[mt] = *(const s16x8*)&As[(wm + mt * 16 + l16) * LDT + quad * 8];
    #pragma unroll
    for (int nt = 0; nt < 4; nt++)
      bf[nt] = *(const s16x8*)&Bs[(wn + nt * 16 + l16) * LDT + quad * 8];
    #pragma unroll
    for (int mt = 0; mt < 4; mt++)
      #pragma unroll
      for (int nt = 0; nt < 4; nt++)
        acc[mt][nt] = __builtin_amdgcn_mfma_f32_16x16x32_bf16(af[mt], bf[nt], acc[mt][nt], 0, 0, 0);
    __syncthreads();
  }

  #pragma unroll
  for (int mt = 0; mt < 4; mt++) {
    #pragma unroll
    for (int nt = 0; nt < 4; nt++) {
      const int col = bn + wn + nt * 16 + l16;
      const float bv = bias[col];
      #pragma unroll
      for (int r = 0; r < 4; r++) {
        const int row = bm + wm + mt * 16 + quad * 4 + r;
        float vv = (acc[mt][nt][r] + bv) * scale;
        if (relu) vv = fmaxf(vv, 0.0f);
        Out[(size_t)row * ostride + col] = f2b(vv);
      }
    }
  }
}

// ---------------- attention: one block per (b, head); thread t owns query t ----------------
__global__ __launch_bounds__(256) void attn_kernel(
    const u16* __restrict__ q, const u16* __restrict__ k, const u16* __restrict__ v,
    const float* __restrict__ src_bias, u16* __restrict__ ctx)
{
  __shared__ u16 ks[S_ * D_];
  __shared__ u16 vs[S_ * D_];
  const int b  = blockIdx.x >> 4;
  const int nh = blockIdx.x & 15;
  const int tid = threadIdx.x;

  for (int i = tid; i < (S_ * D_) / 8; i += 256) {   // 1024 16B-chunks each
    int s = i >> 3, c = (i & 7) * 8;
    *(uint4*)&ks[s * D_ + c] = *(const uint4*)&k[((size_t)(s * B_ + b)) * H_ + nh * D_ + c];
    *(uint4*)&vs[s * D_ + c] = *(const uint4*)&v[((size_t)(s * B_ + b)) * H_ + nh * D_ + c];
  }
  __syncthreads();

  const int t = tid;
  float qf[D_];
  const u16* qp = &q[((size_t)(t * B_ + b)) * H_ + nh * D_];
  #pragma unroll
  for (int c8 = 0; c8 < D_; c8 += 8) {
    uint4 qv = *(const uint4*)&qp[c8];
    const u16* pu = (const u16*)&qv;
    #pragma unroll
    for (int j = 0; j < 8; j++) qf[c8 + j] = b2f(pu[j]);
  }
  const float* bias = src_bias + b * S_;

  // pass 1: online max + denom
  float m = -1e30f, l = 0.0f;
  for (int s = 0; s < S_; s++) {
    float dot = 0.0f;
    #pragma unroll
    for (int d = 0; d < D_; d++) dot += qf[d] * b2f(ks[s * D_ + d]);
    dot += bias[s];
    float nm = fmaxf(m, dot);
    l = l * __expf(m - nm) + __expf(dot - nm);
    m = nm;
  }
  // pass 2: weighted sum of V (recompute logits)
  float of[D_] = {};
  const float inv = 1.0f / l;
  for (int s = 0; s < S_; s++) {
    float dot = 0.0f;
    #pragma unroll
    for (int d = 0; d < D_; d++) dot += qf[d] * b2f(ks[s * D_ + d]);
    dot += bias[s];
    float w = __expf(dot - m) * inv;
    #pragma unroll
    for (int d = 0; d < D_; d++) of[d] += w * b2f(vs[s * D_ + d]);
  }
  u16* op = &ctx[((size_t)(t * B_ + b)) * H_ + nh * D_];
  #pragma unroll
  for (int c8 = 0; c8 < D_; c8 += 8) {
    u16 tmp[8];
    #pragma unroll
    for (int j = 0; j < 8; j++) tmp[j] = f2b(of[c8 + j]);
    *(uint4*)&op[c8] = *(const uint4*)tmp;
  }
}

// ---------------- LSTM step: g = g_x[t] + h @ WhT^T, gate update ----------------
// 64 blocks x 256 thr. Block owns 16 H-cols; wave w computes gate group w (i,j,f,o).
__global__ __launch_bounds__(256) void lstm_step(
    const u16* __restrict__ g_x, const u16* __restrict__ WhT,
    const u16* __restrict__ h_in, u16* __restrict__ h_out,
    float* __restrict__ c, float* __restrict__ out, int t, int last)
{
  __shared__ float g_lds[4][32][16];
  const int bk = blockIdx.x;
  const int tid = threadIdx.x;
  const int wave = tid >> 6, lane = tid & 63;
  const int quad = lane >> 4, l16 = lane & 15;
  const int gb = wave * H_ + bk * 16;      // gate-column base for this wave

  f32x4 acc[2] = {};
  const u16* brow = WhT + (size_t)(gb + l16) * H_;
  const u16* arow0 = h_in + (size_t)l16 * H_;
  const u16* arow1 = h_in + (size_t)(16 + l16) * H_;
  #pragma unroll 4
  for (int kc = 0; kc < 32; kc++) {
    s16x8 bfr = *(const s16x8*)&brow[kc * 32 + quad * 8];
    s16x8 af0 = *(const s16x8*)&arow0[kc * 32 + quad * 8];
    s16x8 af1 = *(const s16x8*)&arow1[kc * 32 + quad * 8];
    acc[0] = __builtin_amdgcn_mfma_f32_16x16x32_bf16(af0, bfr, acc[0], 0, 0, 0);
    acc[1] = __builtin_amdgcn_mfma_f32_16x16x32_bf16(af1, bfr, acc[1], 0, 0, 0);
  }
  #pragma unroll
  for (int mt = 0; mt < 2; mt++)
    #pragma unroll
    for (int r = 0; r < 4; r++) {
      const int row = mt * 16 + quad * 4 + r;   // batch index
      float gx = b2f(g_x[((size_t)t * B_ + row) * (4 * H_) + gb + l16]);
      g_lds[wave][row][l16] = acc[mt][r] + gx;
    }
  __syncthreads();

  for (int idx = tid; idx < B_ * 16; idx += 256) {
    const int b_ = idx >> 4, lc = idx & 15;
    const int col = bk * 16 + lc;
    const float iv = sigm(g_lds[0][b_][lc]);
    const float jv = tanhf(g_lds[1][b_][lc]);
    const float fv = sigm(g_lds[2][b_][lc]);
    const float ov = sigm(g_lds[3][b_][lc]);
    const float cn = fv * c[b_ * H_ + col] + iv * jv;
    const float hn = ov * cn;
    c[b_ * H_ + col] = cn;
    out[(size_t)t * (B_ * H_) + b_ * H_ + col] = hn;
    h_out[b_ * H_ + col] = f2b(hn);
    if (last) {
      out[(size_t)T_ * B_ * H_ + b_ * H_ + col] = cn;                 // c_f
      out[(size_t)T_ * B_ * H_ + B_ * H_ + b_ * H_ + col] = hn;       // h_f
    }
  }
}

extern "C" void kernel_launch(void* const* d_in, const int* in_sizes, int n_in,
                              void* d_out, int out_size, void* d_ws, size_t ws_size,
                              hipStream_t stream)
{
  const float* x        = (const float*)d_in[0];
  const float* src_bias = (const float*)d_in[1];
  // d_in[2] tgt_bias: unused by the reference
  const float* mem      = (const float*)d_in[3];
  const float* Wq = (const float*)d_in[4];  const float* bq = (const float*)d_in[5];
  const float* Wk = (const float*)d_in[6];  const float* bk = (const float*)d_in[7];
  const float* Wv = (const float*)d_in[8];  const float* bv = (const float*)d_in[9];
  const float* Wo = (const float*)d_in[10]; const float* bo = (const float*)d_in[11];
  const float* W1 = (const float*)d_in[12]; const float* b1 = (const float*)d_in[13];
  const float* W2 = (const float*)d_in[14]; const float* b2 = (const float*)d_in[15];
  const float* Wg = (const float*)d_in[16]; const float* bg = (const float*)d_in[17];
  float* out = (float*)d_out;

  char* p = (char*)d_ws;
  u16* xb   = (u16*)p; p += (size_t)TB_ * H_ * 2;        // x bf16 [8192,1024]
  u16* memb = (u16*)p; p += (size_t)SB_ * H_ * 2;        // mem bf16 [4096,1024]
  u16* WqT  = (u16*)p; p += (size_t)H_ * H_ * 2;
  u16* WkT  = (u16*)p; p += (size_t)H_ * H_ * 2;
  u16* WvT  = (u16*)p; p += (size_t)H_ * H_ * 2;
  u16* WoT  = (u16*)p; p += (size_t)H_ * H_ * 2;
  u16* W1T  = (u16*)p; p += (size_t)F_ * H_ * 2;         // [4096,1024]
  u16* W2T  = (u16*)p; p += (size_t)H_ * F_ * 2;         // [1024,4096]
  u16* WgxT = (u16*)p; p += (size_t)(4 * H_) * (2 * H_) * 2;  // [4096,2048]
  u16* WhT  = (u16*)p; p += (size_t)(4 * H_) * H_ * 2;   // [4096,1024]
  u16* qb   = (u16*)p; p += (size_t)TB_ * H_ * 2;
  u16* kb   = (u16*)p; p += (size_t)SB_ * H_ * 2;
  u16* vb   = (u16*)p; p += (size_t)SB_ * H_ * 2;
  u16* ctxb = (u16*)p; p += (size_t)TB_ * H_ * 2;
  u16* xs   = (u16*)p; p += (size_t)TB_ * (2 * H_) * 2;  // [8192,2048] = [ffn | attn]
  u16* h1   = (u16*)p; p += (size_t)TB_ * F_ * 2;        // FFN hidden; later reused as g_x
  float* c  = (float*)p; p += (size_t)B_ * H_ * 4;
  u16* hb0  = (u16*)p; p += (size_t)B_ * H_ * 2;
  u16* hb1  = (u16*)p; p += (size_t)B_ * H_ * 2;
  u16* gx   = h1;   // alias: h1 is dead after FFN2, XG output lands there

  // ---- casts ----
  cast_bf16<<<dim3((TB_ * H_ / 4) / 256), dim3(256), 0, stream>>>(x, xb, TB_ * H_ / 4);
  cast_bf16<<<dim3((SB_ * H_ / 4) / 256), dim3(256), 0, stream>>>(mem, memb, SB_ * H_ / 4);

  // ---- weight transposes (fp32 -> bf16, [R,C] -> [C,R]) ----
  dim3 tb(32, 8);
  transpose_cast<<<dim3(H_ / 32, H_ / 32), tb, 0, stream>>>(Wq, WqT, H_, H_);
  transpose_cast<<<dim3(H_ / 32, H_ / 32), tb, 0, stream>>>(Wk, WkT, H_, H_);
  transpose_cast<<<dim3(H_ / 32, H_ / 32), tb, 0, stream>>>(Wv, WvT, H_, H_);
  transpose_cast<<<dim3(H_ / 32, H_ / 32), tb, 0, stream>>>(Wo, WoT, H_, H_);
  transpose_cast<<<dim3(F_ / 32, H_ / 32), tb, 0, stream>>>(W1, W1T, H_, F_);
  transpose_cast<<<dim3(H_ / 32, F_ / 32), tb, 0, stream>>>(W2, W2T, F_, H_);
  transpose_cast<<<dim3(4 * H_ / 32, 2 * H_ / 32), tb, 0, stream>>>(Wg, WgxT, 2 * H_, 4 * H_);
  transpose_cast<<<dim3(4 * H_ / 32, H_ / 32), tb, 0, stream>>>(Wg + (size_t)(2 * H_) * (4 * H_), WhT, H_, 4 * H_);

  // ---- projections ----
  gemm_bt<<<dim3(H_ / 128, TB_ / 128), 256, 0, stream>>>(xb, WqT, qb, bq, H_, H_, 0.125f, 0);   // *D^-0.5
  gemm_bt<<<dim3(H_ / 128, SB_ / 128), 256, 0, stream>>>(memb, WkT, kb, bk, H_, H_, 1.0f, 0);
  gemm_bt<<<dim3(H_ / 128, SB_ / 128), 256, 0, stream>>>(memb, WvT, vb, bv, H_, H_, 1.0f, 0);

  // ---- attention ----
  attn_kernel<<<dim3(B_ * NH_), 256, 0, stream>>>(qb, kb, vb, src_bias, ctxb);

  // ---- output proj -> xs[:, H:2H] ----
  gemm_bt<<<dim3(H_ / 128, TB_ / 128), 256, 0, stream>>>(ctxb, WoT, xs + H_, bo, H_, 2 * H_, 1.0f, 0);

  // ---- FFN -> xs[:, 0:H] ----
  gemm_bt<<<dim3(F_ / 128, TB_ / 128), 256, 0, stream>>>(xb, W1T, h1, b1, H_, F_, 1.0f, 1);
  gemm_bt<<<dim3(H_ / 128, TB_ / 128), 256, 0, stream>>>(h1, W2T, xs, b2, F_, 2 * H_, 1.0f, 0);

  // ---- gate x-part: g_x = xs @ Wg[0:2H,:] + bg ----
  gemm_bt<<<dim3(4 * H_ / 128, TB_ / 128), 256, 0, stream>>>(xs, WgxT, gx, bg, 2 * H_, 4 * H_, 1.0f, 0);

  // ---- LSTM scan ----
  hipMemsetAsync(c, 0, (size_t)B_ * H_ * 4 + 2 * (size_t)B_ * H_ * 2, stream);  // c, hb0, hb1
  for (int t = 0; t < T_; t++) {
    const u16* hi = (t & 1) ? hb1 : hb0;
    u16* ho       = (t & 1) ? hb0 : hb1;
    lstm_step<<<dim3(64), 256, 0, stream>>>(gx, WhT, hi, ho, c, out, t, t == T_ - 1);
  }
}

// Round 2
// 4504.326 us; speedup vs baseline: 1.0582x; 1.0582x over previous
//
#include <hip/hip_runtime.h>
#include <cstdint>
#include <cstddef>

// Problem constants
#define T_  256
#define S_  128
#define B_  32
#define H_  1024
#define NH_ 16
#define D_  64
#define F_  4096
#define TB_ (T_*B_)   // 8192
#define SB_ (S_*B_)   // 4096

typedef unsigned short u16;
typedef unsigned int   u32;
typedef __attribute__((ext_vector_type(8))) short s16x8;   // 8 bf16 (4 VGPRs)
typedef __attribute__((ext_vector_type(4))) float f32x4;

static __device__ __forceinline__ float b2f(u16 u) {
  union { u32 i; float f; } cv; cv.i = ((u32)u) << 16; return cv.f;
}
static __device__ __forceinline__ u16 f2b(float f) {
  union { float f; u32 i; } cv; cv.f = f;
  u32 u = cv.i;
  u32 r = (u + 0x7fffu + ((u >> 16) & 1u)) >> 16;   // RNE
  return (u16)r;
}
static __device__ __forceinline__ float sigm(float x) {
  return 1.0f / (1.0f + __expf(-x));
}

// async global->LDS DMA, 16B per lane; LDS dest = wave-uniform base + lane*16
typedef const __attribute__((address_space(1))) void* gvoidp;
typedef __attribute__((address_space(3))) void* lvoidp;
static __device__ __forceinline__ void gl_lds16(const void* g, void* l) {
  __builtin_amdgcn_global_load_lds((gvoidp)g, (lvoidp)l, 16, 0, 0);
}

// ---------------- cast fp32 -> bf16 (vectorized x4) ----------------
__global__ void cast_bf16(const float* __restrict__ in, u16* __restrict__ out, int n4) {
  int i = blockIdx.x * 256 + threadIdx.x;
  if (i < n4) {
    float4 v = reinterpret_cast<const float4*>(in)[i];
    ushort4 o;
    o.x = f2b(v.x); o.y = f2b(v.y); o.z = f2b(v.z); o.w = f2b(v.w);
    reinterpret_cast<ushort4*>(out)[i] = o;
  }
}

// ---------------- transpose + cast: in fp32 [R,C] -> out bf16 [C,R] ----------------
__global__ void transpose_cast(const float* __restrict__ in, u16* __restrict__ out,
                               int R, int C) {
  __shared__ float tile[32][33];
  int c0 = blockIdx.x * 32, r0 = blockIdx.y * 32;
  int tx = threadIdx.x, ty = threadIdx.y;
  #pragma unroll
  for (int k = 0; k < 32; k += 8)
    tile[ty + k][tx] = in[(size_t)(r0 + ty + k) * C + c0 + tx];
  __syncthreads();
  #pragma unroll
  for (int k = 0; k < 32; k += 8)
    out[(size_t)(c0 + ty + k) * R + r0 + tx] = f2b(tile[tx][ty + k]);
}

// ---------------- GEMM: Out[M,N] = act((A[M,K] @ Bt[N,K]^T + bias) * scale) ----------------
// m97 structure: 128x128 tile, global_load_lds width-16 staging (UNPADDED LDS:
// the DMA lands at base+lane*16, so layout must be lane-contiguous), 4 waves 2x2,
// 16x16x32 bf16 MFMA.
__global__ __launch_bounds__(256) void gemm_bt(
    const u16* __restrict__ A, const u16* __restrict__ Bt,
    u16* __restrict__ Out, const float* __restrict__ bias,
    int Kdim, int ostride, float scale, int relu)
{
  __shared__ __align__(16) u16 As[128 * 32];
  __shared__ __align__(16) u16 Bs[128 * 32];
  const int tid  = threadIdx.x;
  const int wave = tid >> 6, lane = tid & 63;
  const int quad = lane >> 4, l16 = lane & 15;
  const int bm = blockIdx.y << 7, bn = blockIdx.x << 7;
  const int wm = (wave & 1) << 6, wn = (wave >> 1) << 6;
  f32x4 acc[4][4] = {};

  // staging: wave w covers tile rows [w*32, w*32+32); lane i -> row w*32 + i/4,
  // col elems (i&3)*8. LDS byte dest = w*2048 + i*16  == row*64 + (i&3)*16. Exact match.
  const int sr = wave * 32 + (lane >> 2);
  const int sc = (lane & 3) * 8;
  const u16* ga = &A [(size_t)(bm + sr) * Kdim + sc];
  const u16* gb = &Bt[(size_t)(bn + sr) * Kdim + sc];
  u16* lA = &As[wave * 1024];
  u16* lB = &Bs[wave * 1024];
  const size_t rowskip = (size_t)16 * Kdim;

  for (int k0 = 0; k0 < Kdim; k0 += 32) {
    gl_lds16(ga + k0,           lA);
    gl_lds16(ga + k0 + rowskip, lA + 512);
    gl_lds16(gb + k0,           lB);
    gl_lds16(gb + k0 + rowskip, lB + 512);
    __syncthreads();   // waits vmcnt(0): DMA landed
    s16x8 af[4], bf[4];
    #pragma unroll
    for (int mt = 0; mt < 4; mt++)
      af[mt] = *(const s16x8*)&As[(wm + mt * 16 + l16) * 32 + quad * 8];
    #pragma unroll
    for (int nt = 0; nt < 4; nt++)
      bf[nt] = *(const s16x8*)&Bs[(wn + nt * 16 + l16) * 32 + quad * 8];
    #pragma unroll
    for (int mt = 0; mt < 4; mt++)
      #pragma unroll
      for (int nt = 0; nt < 4; nt++)
        acc[mt][nt] = __builtin_amdgcn_mfma_f32_16x16x32_bf16(af[mt], bf[nt], acc[mt][nt], 0, 0, 0);
    __syncthreads();
  }

  #pragma unroll
  for (int mt = 0; mt < 4; mt++) {
    #pragma unroll
    for (int nt = 0; nt < 4; nt++) {
      const int col = bn + wn + nt * 16 + l16;
      const float bv = bias[col];
      #pragma unroll
      for (int r = 0; r < 4; r++) {
        const int row = bm + wm + mt * 16 + quad * 4 + r;
        float vv = (acc[mt][nt][r] + bv) * scale;
        if (relu) vv = fmaxf(vv, 0.0f);
        Out[(size_t)row * ostride + col] = f2b(vv);
      }
    }
  }
}

// ---------------- attention: one block per (b, head); thread t owns query t ----------------
__global__ __launch_bounds__(256) void attn_kernel(
    const u16* __restrict__ q, const u16* __restrict__ k, const u16* __restrict__ v,
    const float* __restrict__ src_bias, u16* __restrict__ ctx)
{
  __shared__ u16 ks[S_ * D_];
  __shared__ u16 vs[S_ * D_];
  const int b  = blockIdx.x >> 4;
  const int nh = blockIdx.x & 15;
  const int tid = threadIdx.x;

  for (int i = tid; i < (S_ * D_) / 8; i += 256) {
    int s = i >> 3, c = (i & 7) * 8;
    *(uint4*)&ks[s * D_ + c] = *(const uint4*)&k[((size_t)(s * B_ + b)) * H_ + nh * D_ + c];
    *(uint4*)&vs[s * D_ + c] = *(const uint4*)&v[((size_t)(s * B_ + b)) * H_ + nh * D_ + c];
  }
  __syncthreads();

  const int t = tid;
  float qf[D_];
  const u16* qp = &q[((size_t)(t * B_ + b)) * H_ + nh * D_];
  #pragma unroll
  for (int c8 = 0; c8 < D_; c8 += 8) {
    uint4 qv = *(const uint4*)&qp[c8];
    const u16* pu = (const u16*)&qv;
    #pragma unroll
    for (int j = 0; j < 8; j++) qf[c8 + j] = b2f(pu[j]);
  }
  const float* bias = src_bias + b * S_;

  float m = -1e30f, l = 0.0f;
  for (int s = 0; s < S_; s++) {
    float dot = 0.0f;
    #pragma unroll
    for (int d = 0; d < D_; d++) dot += qf[d] * b2f(ks[s * D_ + d]);
    dot += bias[s];
    float nm = fmaxf(m, dot);
    l = l * __expf(m - nm) + __expf(dot - nm);
    m = nm;
  }
  float of[D_] = {};
  const float inv = 1.0f / l;
  for (int s = 0; s < S_; s++) {
    float dot = 0.0f;
    #pragma unroll
    for (int d = 0; d < D_; d++) dot += qf[d] * b2f(ks[s * D_ + d]);
    dot += bias[s];
    float w = __expf(dot - m) * inv;
    #pragma unroll
    for (int d = 0; d < D_; d++) of[d] += w * b2f(vs[s * D_ + d]);
  }
  u16* op = &ctx[((size_t)(t * B_ + b)) * H_ + nh * D_];
  #pragma unroll
  for (int c8 = 0; c8 < D_; c8 += 8) {
    u16 tmp[8];
    #pragma unroll
    for (int j = 0; j < 8; j++) tmp[j] = f2b(of[c8 + j]);
    *(uint4*)&op[c8] = *(const uint4*)tmp;
  }
}

// ---------------- persistent LSTM: 64 blocks, WhT slice resident in LDS ----------------
// Block bk owns H-cols [bk*16, bk*16+16) of all 4 gates; wave w = gate w.
// c state in registers; h exchanged via global double-buffer + grid barrier.
// 64 blocks x 140KB LDS => 1 block/CU, 64 <= 256 CUs => co-resident (barrier safe).
#define LW_ 1032   // padded LDS row stride (elems): stride 2064B -> ~2-way conflicts (free)
__global__ __launch_bounds__(256) void lstm_persistent(
    const u16* __restrict__ g_x, const u16* __restrict__ WhT,
    u16* __restrict__ hb0, u16* __restrict__ hb1,
    float* __restrict__ out, int* bar)
{
  __shared__ __align__(16) u16 Wlds[4 * 16 * LW_];   // 132096 B
  __shared__ float g_lds[4][32][16];                  // 8 KB
  const int bk = blockIdx.x, tid = threadIdx.x;
  const int wave = tid >> 6, lane = tid & 63;
  const int quad = lane >> 4, l16 = lane & 15;
  const int gb = wave * H_ + bk * 16;   // gate-col base in [0,4H)

  // stage WhT rows [gb, gb+16) into LDS (once)
  for (int i = lane; i < 16 * (H_ / 8); i += 64) {
    int r = i >> 7, cb = (i & 127) << 3;
    *(uint4*)&Wlds[(wave * 16 + r) * LW_ + cb] = *(const uint4*)&WhT[(size_t)(gb + r) * H_ + cb];
  }
  __syncthreads();

  float creg[2] = {0.0f, 0.0f};
  // pointwise ownership: idx = tid + ii*256 -> batch idx>>4, local col idx&15
  const int pb0 = tid >> 4, pc0 = tid & 15;

  for (int t = 0; t < T_; t++) {
    const u16* hin = (t & 1) ? hb0 : hb1;   // h written at step t-1
    u16* hout      = (t & 1) ? hb1 : hb0;

    if (t > 0) {
      f32x4 acc[2] = {};
      const u16* wrow  = &Wlds[(wave * 16 + l16) * LW_];
      const u16* arow0 = &hin[(size_t)l16 * H_];
      const u16* arow1 = &hin[(size_t)(16 + l16) * H_];
      #pragma unroll 8
      for (int kc = 0; kc < 32; kc++) {
        s16x8 bfr = *(const s16x8*)&wrow [kc * 32 + quad * 8];
        s16x8 af0 = *(const s16x8*)&arow0[kc * 32 + quad * 8];
        s16x8 af1 = *(const s16x8*)&arow1[kc * 32 + quad * 8];
        acc[0] = __builtin_amdgcn_mfma_f32_16x16x32_bf16(af0, bfr, acc[0], 0, 0, 0);
        acc[1] = __builtin_amdgcn_mfma_f32_16x16x32_bf16(af1, bfr, acc[1], 0, 0, 0);
      }
      #pragma unroll
      for (int mt = 0; mt < 2; mt++)
        #pragma unroll
        for (int r = 0; r < 4; r++) {
          const int row = mt * 16 + quad * 4 + r;   // batch
          float gx = b2f(g_x[((size_t)t * B_ + row) * (4 * H_) + gb + l16]);
          g_lds[wave][row][l16] = acc[mt][r] + gx;
        }
    } else {
      // t == 0: h = 0 -> g = g_x
      #pragma unroll
      for (int mt = 0; mt < 2; mt++)
        #pragma unroll
        for (int r = 0; r < 4; r++) {
          const int row = mt * 16 + quad * 4 + r;
          g_lds[wave][row][l16] = b2f(g_x[((size_t)row) * (4 * H_) + gb + l16]);
        }
    }
    __syncthreads();

    #pragma unroll
    for (int ii = 0; ii < 2; ii++) {
      const int b_ = pb0 + ii * 16;       // tid>>4 in [0,16) + 16
      const int lc = pc0;
      const int col = bk * 16 + lc;
      const float iv = sigm(g_lds[0][b_][lc]);
      const float jv = tanhf(g_lds[1][b_][lc]);
      const float fv = sigm(g_lds[2][b_][lc]);
      const float ov = sigm(g_lds[3][b_][lc]);
      const float cn = fv * creg[ii] + iv * jv;
      const float hn = ov * cn;
      creg[ii] = cn;
      out[(size_t)t * (B_ * H_) + b_ * H_ + col] = hn;
      hout[(size_t)b_ * H_ + col] = f2b(hn);
      if (t == T_ - 1) {
        out[(size_t)T_ * B_ * H_ + b_ * H_ + col] = cn;              // c_f
        out[(size_t)T_ * B_ * H_ + B_ * H_ + b_ * H_ + col] = hn;    // h_f
      }
    }

    if (t < T_ - 1) {
      __syncthreads();                    // all waves' h stores issued & complete (vmcnt drained at barrier)
      if (tid == 0) {
        __threadfence();                  // device-scope release: L2 writeback
        atomicAdd(bar, 1);                // device scope by default
        const int target = 64 * (t + 1);
        while (__hip_atomic_load(bar, __ATOMIC_ACQUIRE, __HIP_MEMORY_SCOPE_AGENT) < target) { }
      }
      __syncthreads();                    // acquire visible to whole block
    }
  }
}

extern "C" void kernel_launch(void* const* d_in, const int* in_sizes, int n_in,
                              void* d_out, int out_size, void* d_ws, size_t ws_size,
                              hipStream_t stream)
{
  const float* x        = (const float*)d_in[0];
  const float* src_bias = (const float*)d_in[1];
  // d_in[2] tgt_bias: unused by the reference
  const float* mem      = (const float*)d_in[3];
  const float* Wq = (const float*)d_in[4];  const float* bq = (const float*)d_in[5];
  const float* Wk = (const float*)d_in[6];  const float* bk = (const float*)d_in[7];
  const float* Wv = (const float*)d_in[8];  const float* bv = (const float*)d_in[9];
  const float* Wo = (const float*)d_in[10]; const float* bo = (const float*)d_in[11];
  const float* W1 = (const float*)d_in[12]; const float* b1 = (const float*)d_in[13];
  const float* W2 = (const float*)d_in[14]; const float* b2 = (const float*)d_in[15];
  const float* Wg = (const float*)d_in[16]; const float* bg = (const float*)d_in[17];
  float* out = (float*)d_out;

  char* p = (char*)d_ws;
  u16* xb   = (u16*)p; p += (size_t)TB_ * H_ * 2;
  u16* memb = (u16*)p; p += (size_t)SB_ * H_ * 2;
  u16* WqT  = (u16*)p; p += (size_t)H_ * H_ * 2;
  u16* WkT  = (u16*)p; p += (size_t)H_ * H_ * 2;
  u16* WvT  = (u16*)p; p += (size_t)H_ * H_ * 2;
  u16* WoT  = (u16*)p; p += (size_t)H_ * H_ * 2;
  u16* W1T  = (u16*)p; p += (size_t)F_ * H_ * 2;
  u16* W2T  = (u16*)p; p += (size_t)H_ * F_ * 2;
  u16* WgxT = (u16*)p; p += (size_t)(4 * H_) * (2 * H_) * 2;
  u16* WhT  = (u16*)p; p += (size_t)(4 * H_) * H_ * 2;
  u16* qb   = (u16*)p; p += (size_t)TB_ * H_ * 2;
  u16* kb   = (u16*)p; p += (size_t)SB_ * H_ * 2;
  u16* vb   = (u16*)p; p += (size_t)SB_ * H_ * 2;
  u16* ctxb = (u16*)p; p += (size_t)TB_ * H_ * 2;
  u16* xs   = (u16*)p; p += (size_t)TB_ * (2 * H_) * 2;
  u16* h1   = (u16*)p; p += (size_t)TB_ * F_ * 2;    // FFN hidden; reused as g_x
  u16* hb0  = (u16*)p; p += (size_t)B_ * H_ * 2;
  u16* hb1  = (u16*)p; p += (size_t)B_ * H_ * 2;
  int* bar  = (int*)p; p += 256;
  u16* gx   = h1;

  // ---- casts ----
  cast_bf16<<<dim3((TB_ * H_ / 4) / 256), dim3(256), 0, stream>>>(x, xb, TB_ * H_ / 4);
  cast_bf16<<<dim3((SB_ * H_ / 4) / 256), dim3(256), 0, stream>>>(mem, memb, SB_ * H_ / 4);

  // ---- weight transposes ----
  dim3 tb(32, 8);
  transpose_cast<<<dim3(H_ / 32, H_ / 32), tb, 0, stream>>>(Wq, WqT, H_, H_);
  transpose_cast<<<dim3(H_ / 32, H_ / 32), tb, 0, stream>>>(Wk, WkT, H_, H_);
  transpose_cast<<<dim3(H_ / 32, H_ / 32), tb, 0, stream>>>(Wv, WvT, H_, H_);
  transpose_cast<<<dim3(H_ / 32, H_ / 32), tb, 0, stream>>>(Wo, WoT, H_, H_);
  transpose_cast<<<dim3(F_ / 32, H_ / 32), tb, 0, stream>>>(W1, W1T, H_, F_);
  transpose_cast<<<dim3(H_ / 32, F_ / 32), tb, 0, stream>>>(W2, W2T, F_, H_);
  transpose_cast<<<dim3(4 * H_ / 32, 2 * H_ / 32), tb, 0, stream>>>(Wg, WgxT, 2 * H_, 4 * H_);
  transpose_cast<<<dim3(4 * H_ / 32, H_ / 32), tb, 0, stream>>>(Wg + (size_t)(2 * H_) * (4 * H_), WhT, H_, 4 * H_);

  // ---- projections ----
  gemm_bt<<<dim3(H_ / 128, TB_ / 128), 256, 0, stream>>>(xb, WqT, qb, bq, H_, H_, 0.125f, 0);
  gemm_bt<<<dim3(H_ / 128, SB_ / 128), 256, 0, stream>>>(memb, WkT, kb, bk, H_, H_, 1.0f, 0);
  gemm_bt<<<dim3(H_ / 128, SB_ / 128), 256, 0, stream>>>(memb, WvT, vb, bv, H_, H_, 1.0f, 0);

  // ---- attention ----
  attn_kernel<<<dim3(B_ * NH_), 256, 0, stream>>>(qb, kb, vb, src_bias, ctxb);

  // ---- output proj -> xs[:, H:2H] ----
  gemm_bt<<<dim3(H_ / 128, TB_ / 128), 256, 0, stream>>>(ctxb, WoT, xs + H_, bo, H_, 2 * H_, 1.0f, 0);

  // ---- FFN -> xs[:, 0:H] ----
  gemm_bt<<<dim3(F_ / 128, TB_ / 128), 256, 0, stream>>>(xb, W1T, h1, b1, H_, F_, 1.0f, 1);
  gemm_bt<<<dim3(H_ / 128, TB_ / 128), 256, 0, stream>>>(h1, W2T, xs, b2, F_, 2 * H_, 1.0f, 0);

  // ---- gate x-part ----
  gemm_bt<<<dim3(4 * H_ / 128, TB_ / 128), 256, 0, stream>>>(xs, WgxT, gx, bg, 2 * H_, 4 * H_, 1.0f, 0);

  // ---- persistent LSTM ----
  hipMemsetAsync(bar, 0, 256, stream);
  lstm_persistent<<<dim3(64), 256, 0, stream>>>(gx, WhT, hb0, hb1, out, bar);
}

// Round 3
// 2660.744 us; speedup vs baseline: 1.7915x; 1.6929x over previous
//
#include <hip/hip_runtime.h>
#include <cstdint>
#include <cstddef>

// Problem constants
#define T_  256
#define S_  128
#define B_  32
#define H_  1024
#define NH_ 16
#define D_  64
#define F_  4096
#define TB_ (T_*B_)   // 8192
#define SB_ (S_*B_)   // 4096

typedef unsigned short u16;
typedef unsigned int   u32;
typedef unsigned long long u64;
typedef __attribute__((ext_vector_type(8))) short s16x8;   // 8 bf16 (4 VGPRs)
typedef __attribute__((ext_vector_type(4))) float f32x4;

static __device__ __forceinline__ float b2f(u16 u) {
  union { u32 i; float f; } cv; cv.i = ((u32)u) << 16; return cv.f;
}
static __device__ __forceinline__ u16 f2b(float f) {
  union { float f; u32 i; } cv; cv.f = f;
  u32 u = cv.i;
  u32 r = (u + 0x7fffu + ((u >> 16) & 1u)) >> 16;   // RNE
  return (u16)r;
}
static __device__ __forceinline__ float sigm(float x) {
  return 1.0f / (1.0f + __expf(-x));
}

// async global->LDS DMA, 16B per lane; LDS dest = wave-uniform base + lane*16
typedef const __attribute__((address_space(1))) void* gvoidp;
typedef __attribute__((address_space(3))) void* lvoidp;
static __device__ __forceinline__ void gl_lds16(const void* g, void* l) {
  __builtin_amdgcn_global_load_lds((gvoidp)g, (lvoidp)l, 16, 0, 0);
}

// 16B load as two relaxed agent-scope (sc1, device-coherent) 8B atomic loads.
// No fences needed: relaxed atomics are coherent at agent scope by themselves.
static __device__ __forceinline__ s16x8 ld_h16(const u16* p) {
  union { s16x8 v; u64 q[2]; } r;
  u64* q = (u64*)p;
  r.q[0] = __hip_atomic_load(q,     __ATOMIC_RELAXED, __HIP_MEMORY_SCOPE_AGENT);
  r.q[1] = __hip_atomic_load(q + 1, __ATOMIC_RELAXED, __HIP_MEMORY_SCOPE_AGENT);
  return r.v;
}
static __device__ __forceinline__ void st_h2(u16* p, u16 v) {
  __hip_atomic_store(p, v, __ATOMIC_RELAXED, __HIP_MEMORY_SCOPE_AGENT);
}

// ---------------- cast fp32 -> bf16 (vectorized x4) ----------------
__global__ void cast_bf16(const float* __restrict__ in, u16* __restrict__ out, int n4) {
  int i = blockIdx.x * 256 + threadIdx.x;
  if (i < n4) {
    float4 v = reinterpret_cast<const float4*>(in)[i];
    ushort4 o;
    o.x = f2b(v.x); o.y = f2b(v.y); o.z = f2b(v.z); o.w = f2b(v.w);
    reinterpret_cast<ushort4*>(out)[i] = o;
  }
}

// ---------------- transpose + cast: in fp32 [R,C] -> out bf16 [C,R] ----------------
__global__ void transpose_cast(const float* __restrict__ in, u16* __restrict__ out,
                               int R, int C) {
  __shared__ float tile[32][33];
  int c0 = blockIdx.x * 32, r0 = blockIdx.y * 32;
  int tx = threadIdx.x, ty = threadIdx.y;
  #pragma unroll
  for (int k = 0; k < 32; k += 8)
    tile[ty + k][tx] = in[(size_t)(r0 + ty + k) * C + c0 + tx];
  __syncthreads();
  #pragma unroll
  for (int k = 0; k < 32; k += 8)
    out[(size_t)(c0 + ty + k) * R + r0 + tx] = f2b(tile[tx][ty + k]);
}

// ---------------- GEMM: Out[M,N] = act((A[M,K] @ Bt[N,K]^T + bias) * scale) ----------------
__global__ __launch_bounds__(256) void gemm_bt(
    const u16* __restrict__ A, const u16* __restrict__ Bt,
    u16* __restrict__ Out, const float* __restrict__ bias,
    int Kdim, int ostride, float scale, int relu)
{
  __shared__ __align__(16) u16 As[128 * 32];
  __shared__ __align__(16) u16 Bs[128 * 32];
  const int tid  = threadIdx.x;
  const int wave = tid >> 6, lane = tid & 63;
  const int quad = lane >> 4, l16 = lane & 15;
  const int bm = blockIdx.y << 7, bn = blockIdx.x << 7;
  const int wm = (wave & 1) << 6, wn = (wave >> 1) << 6;
  f32x4 acc[4][4] = {};

  const int sr = wave * 32 + (lane >> 2);
  const int sc = (lane & 3) * 8;
  const u16* ga = &A [(size_t)(bm + sr) * Kdim + sc];
  const u16* gb = &Bt[(size_t)(bn + sr) * Kdim + sc];
  u16* lA = &As[wave * 1024];
  u16* lB = &Bs[wave * 1024];
  const size_t rowskip = (size_t)16 * Kdim;

  for (int k0 = 0; k0 < Kdim; k0 += 32) {
    gl_lds16(ga + k0,           lA);
    gl_lds16(ga + k0 + rowskip, lA + 512);
    gl_lds16(gb + k0,           lB);
    gl_lds16(gb + k0 + rowskip, lB + 512);
    __syncthreads();
    s16x8 af[4], bf[4];
    #pragma unroll
    for (int mt = 0; mt < 4; mt++)
      af[mt] = *(const s16x8*)&As[(wm + mt * 16 + l16) * 32 + quad * 8];
    #pragma unroll
    for (int nt = 0; nt < 4; nt++)
      bf[nt] = *(const s16x8*)&Bs[(wn + nt * 16 + l16) * 32 + quad * 8];
    #pragma unroll
    for (int mt = 0; mt < 4; mt++)
      #pragma unroll
      for (int nt = 0; nt < 4; nt++)
        acc[mt][nt] = __builtin_amdgcn_mfma_f32_16x16x32_bf16(af[mt], bf[nt], acc[mt][nt], 0, 0, 0);
    __syncthreads();
  }

  #pragma unroll
  for (int mt = 0; mt < 4; mt++) {
    #pragma unroll
    for (int nt = 0; nt < 4; nt++) {
      const int col = bn + wn + nt * 16 + l16;
      const float bv = bias[col];
      #pragma unroll
      for (int r = 0; r < 4; r++) {
        const int row = bm + wm + mt * 16 + quad * 4 + r;
        float vv = (acc[mt][nt][r] + bv) * scale;
        if (relu) vv = fmaxf(vv, 0.0f);
        Out[(size_t)row * ostride + col] = f2b(vv);
      }
    }
  }
}

// ---------------- attention: one block per (b, head); thread t owns query t ----------------
__global__ __launch_bounds__(256) void attn_kernel(
    const u16* __restrict__ q, const u16* __restrict__ k, const u16* __restrict__ v,
    const float* __restrict__ src_bias, u16* __restrict__ ctx)
{
  __shared__ u16 ks[S_ * D_];
  __shared__ u16 vs[S_ * D_];
  const int b  = blockIdx.x >> 4;
  const int nh = blockIdx.x & 15;
  const int tid = threadIdx.x;

  for (int i = tid; i < (S_ * D_) / 8; i += 256) {
    int s = i >> 3, c = (i & 7) * 8;
    *(uint4*)&ks[s * D_ + c] = *(const uint4*)&k[((size_t)(s * B_ + b)) * H_ + nh * D_ + c];
    *(uint4*)&vs[s * D_ + c] = *(const uint4*)&v[((size_t)(s * B_ + b)) * H_ + nh * D_ + c];
  }
  __syncthreads();

  const int t = tid;
  float qf[D_];
  const u16* qp = &q[((size_t)(t * B_ + b)) * H_ + nh * D_];
  #pragma unroll
  for (int c8 = 0; c8 < D_; c8 += 8) {
    uint4 qv = *(const uint4*)&qp[c8];
    const u16* pu = (const u16*)&qv;
    #pragma unroll
    for (int j = 0; j < 8; j++) qf[c8 + j] = b2f(pu[j]);
  }
  const float* bias = src_bias + b * S_;

  float m = -1e30f, l = 0.0f;
  for (int s = 0; s < S_; s++) {
    float dot = 0.0f;
    #pragma unroll
    for (int d = 0; d < D_; d++) dot += qf[d] * b2f(ks[s * D_ + d]);
    dot += bias[s];
    float nm = fmaxf(m, dot);
    l = l * __expf(m - nm) + __expf(dot - nm);
    m = nm;
  }
  float of[D_] = {};
  const float inv = 1.0f / l;
  for (int s = 0; s < S_; s++) {
    float dot = 0.0f;
    #pragma unroll
    for (int d = 0; d < D_; d++) dot += qf[d] * b2f(ks[s * D_ + d]);
    dot += bias[s];
    float w = __expf(dot - m) * inv;
    #pragma unroll
    for (int d = 0; d < D_; d++) of[d] += w * b2f(vs[s * D_ + d]);
  }
  u16* op = &ctx[((size_t)(t * B_ + b)) * H_ + nh * D_];
  #pragma unroll
  for (int c8 = 0; c8 < D_; c8 += 8) {
    u16 tmp[8];
    #pragma unroll
    for (int j = 0; j < 8; j++) tmp[j] = f2b(of[c8 + j]);
    *(uint4*)&op[c8] = *(const uint4*)tmp;
  }
}

// ---------------- persistent LSTM v2 ----------------
// 64 blocks x 256 thr, 1/CU. Block bk owns H-cols [bk*16,+16) of all 4 gates.
// Weights live in VGPRs (128/wave, loaded once). K-SPLIT: wave w handles
// k in [w*256,+256) for all 64 gate-cols -> h read exactly once per block.
// h via relaxed agent-scope (sc1) atomics -> no L2 fences in the loop.
// Split-phase barrier: arrive, prefetch g_x[t+1], then poll relaxed.
__global__ __launch_bounds__(256, 1) void lstm_persistent(
    const u16* __restrict__ g_x, const u16* __restrict__ WhT,
    u16* __restrict__ hb0, u16* __restrict__ hb1,
    float* __restrict__ out, int* bar)
{
  __shared__ float P[4][4][32][17];   // [k-wave][gate][batch][col] padded: 34 KB
  const int bk = blockIdx.x, tid = threadIdx.x;
  const int wave = tid >> 6, lane = tid & 63;
  const int quad = lane >> 4, l16 = lane & 15;

  // ---- one-time weight preload into VGPRs ----
  // B-frag for gate g, k-chunk kc: W[n=g*1024+bk*16+l16][k=wave*256+kc*32+quad*8 ..+8]
  s16x8 wfrag[4][8];
  #pragma unroll
  for (int g = 0; g < 4; g++)
    #pragma unroll
    for (int kc = 0; kc < 8; kc++)
      wfrag[g][kc] = *(const s16x8*)&WhT[(size_t)(g * H_ + bk * 16 + l16) * H_ +
                                         wave * 256 + kc * 32 + quad * 8];

  const int pb = tid >> 4;        // batch 0..15 (+16 for second output)
  const int pc = tid & 15;        // local col
  const int col = bk * 16 + pc;
  float creg[2] = {0.0f, 0.0f};

  // prefetch g_x for t=0
  float gxp[2][4];
  #pragma unroll
  for (int ii = 0; ii < 2; ii++)
    #pragma unroll
    for (int g = 0; g < 4; g++)
      gxp[ii][g] = b2f(g_x[((size_t)(pb + ii * 16)) * (4 * H_) + g * H_ + col]);

  for (int t = 0; t < T_; t++) {
    const u16* hin = (t & 1) ? hb0 : hb1;
    u16* hout      = (t & 1) ? hb1 : hb0;

    if (t > 0) {
      // ---- gate GEMM, K-split ----
      f32x4 acc[4][2] = {};
      const u16* hbase = hin + wave * 256 + quad * 8;
      #pragma unroll
      for (int kc = 0; kc < 8; kc++) {
        s16x8 a0 = ld_h16(&hbase[(size_t)l16 * H_ + kc * 32]);
        s16x8 a1 = ld_h16(&hbase[(size_t)(16 + l16) * H_ + kc * 32]);
        #pragma unroll
        for (int g = 0; g < 4; g++) {
          acc[g][0] = __builtin_amdgcn_mfma_f32_16x16x32_bf16(a0, wfrag[g][kc], acc[g][0], 0, 0, 0);
          acc[g][1] = __builtin_amdgcn_mfma_f32_16x16x32_bf16(a1, wfrag[g][kc], acc[g][1], 0, 0, 0);
        }
      }
      #pragma unroll
      for (int g = 0; g < 4; g++)
        #pragma unroll
        for (int mt = 0; mt < 2; mt++)
          #pragma unroll
          for (int r = 0; r < 4; r++)
            P[wave][g][mt * 16 + quad * 4 + r][l16] = acc[g][mt][r];
      __syncthreads();
    }

    // ---- reduce partials + pointwise ----
    #pragma unroll
    for (int ii = 0; ii < 2; ii++) {
      const int b_ = pb + ii * 16;
      float gs[4];
      #pragma unroll
      for (int g = 0; g < 4; g++) {
        float s = gxp[ii][g];
        if (t > 0) s += P[0][g][b_][pc] + P[1][g][b_][pc] + P[2][g][b_][pc] + P[3][g][b_][pc];
        gs[g] = s;
      }
      const float iv = sigm(gs[0]);
      const float jv = tanhf(gs[1]);
      const float fv = sigm(gs[2]);
      const float ov = sigm(gs[3]);
      const float cn = fv * creg[ii] + iv * jv;
      const float hn = ov * cn;
      creg[ii] = cn;
      out[(size_t)t * (B_ * H_) + b_ * H_ + col] = hn;
      st_h2(&hout[(size_t)b_ * H_ + col], f2b(hn));
      if (t == T_ - 1) {
        out[(size_t)T_ * B_ * H_ + b_ * H_ + col] = cn;              // c_f
        out[(size_t)T_ * B_ * H_ + B_ * H_ + b_ * H_ + col] = hn;    // h_f
      }
    }

    if (t < T_ - 1) {
      asm volatile("s_waitcnt vmcnt(0)" ::: "memory");   // h sc1-stores at coherence point
      __syncthreads();                                   // whole block's h published
      if (tid == 0)
        __hip_atomic_fetch_add(bar, 1, __ATOMIC_RELAXED, __HIP_MEMORY_SCOPE_AGENT);
      // prefetch g_x for t+1 while waiting
      #pragma unroll
      for (int ii = 0; ii < 2; ii++)
        #pragma unroll
        for (int g = 0; g < 4; g++)
          gxp[ii][g] = b2f(g_x[((size_t)(t + 1) * B_ + pb + ii * 16) * (4 * H_) + g * H_ + col]);
      if (tid == 0) {
        const int target = 64 * (t + 1);
        while (__hip_atomic_load(bar, __ATOMIC_RELAXED, __HIP_MEMORY_SCOPE_AGENT) < target) { }
      }
      __syncthreads();
    }
  }
}

extern "C" void kernel_launch(void* const* d_in, const int* in_sizes, int n_in,
                              void* d_out, int out_size, void* d_ws, size_t ws_size,
                              hipStream_t stream)
{
  const float* x        = (const float*)d_in[0];
  const float* src_bias = (const float*)d_in[1];
  const float* mem      = (const float*)d_in[3];
  const float* Wq = (const float*)d_in[4];  const float* bq = (const float*)d_in[5];
  const float* Wk = (const float*)d_in[6];  const float* bk = (const float*)d_in[7];
  const float* Wv = (const float*)d_in[8];  const float* bv = (const float*)d_in[9];
  const float* Wo = (const float*)d_in[10]; const float* bo = (const float*)d_in[11];
  const float* W1 = (const float*)d_in[12]; const float* b1 = (const float*)d_in[13];
  const float* W2 = (const float*)d_in[14]; const float* b2 = (const float*)d_in[15];
  const float* Wg = (const float*)d_in[16]; const float* bg = (const float*)d_in[17];
  float* out = (float*)d_out;

  char* p = (char*)d_ws;
  u16* xb   = (u16*)p; p += (size_t)TB_ * H_ * 2;
  u16* memb = (u16*)p; p += (size_t)SB_ * H_ * 2;
  u16* WqT  = (u16*)p; p += (size_t)H_ * H_ * 2;
  u16* WkT  = (u16*)p; p += (size_t)H_ * H_ * 2;
  u16* WvT  = (u16*)p; p += (size_t)H_ * H_ * 2;
  u16* WoT  = (u16*)p; p += (size_t)H_ * H_ * 2;
  u16* W1T  = (u16*)p; p += (size_t)F_ * H_ * 2;
  u16* W2T  = (u16*)p; p += (size_t)H_ * F_ * 2;
  u16* WgxT = (u16*)p; p += (size_t)(4 * H_) * (2 * H_) * 2;
  u16* WhT  = (u16*)p; p += (size_t)(4 * H_) * H_ * 2;
  u16* qb   = (u16*)p; p += (size_t)TB_ * H_ * 2;
  u16* kb   = (u16*)p; p += (size_t)SB_ * H_ * 2;
  u16* vb   = (u16*)p; p += (size_t)SB_ * H_ * 2;
  u16* ctxb = (u16*)p; p += (size_t)TB_ * H_ * 2;
  u16* xs   = (u16*)p; p += (size_t)TB_ * (2 * H_) * 2;
  u16* h1   = (u16*)p; p += (size_t)TB_ * F_ * 2;    // FFN hidden; reused as g_x
  u16* hb0  = (u16*)p; p += (size_t)B_ * H_ * 2;
  u16* hb1  = (u16*)p; p += (size_t)B_ * H_ * 2;
  int* bar  = (int*)p; p += 256;
  u16* gx   = h1;

  // ---- casts ----
  cast_bf16<<<dim3((TB_ * H_ / 4) / 256), dim3(256), 0, stream>>>(x, xb, TB_ * H_ / 4);
  cast_bf16<<<dim3((SB_ * H_ / 4) / 256), dim3(256), 0, stream>>>(mem, memb, SB_ * H_ / 4);

  // ---- weight transposes ----
  dim3 tb(32, 8);
  transpose_cast<<<dim3(H_ / 32, H_ / 32), tb, 0, stream>>>(Wq, WqT, H_, H_);
  transpose_cast<<<dim3(H_ / 32, H_ / 32), tb, 0, stream>>>(Wk, WkT, H_, H_);
  transpose_cast<<<dim3(H_ / 32, H_ / 32), tb, 0, stream>>>(Wv, WvT, H_, H_);
  transpose_cast<<<dim3(H_ / 32, H_ / 32), tb, 0, stream>>>(Wo, WoT, H_, H_);
  transpose_cast<<<dim3(F_ / 32, H_ / 32), tb, 0, stream>>>(W1, W1T, H_, F_);
  transpose_cast<<<dim3(H_ / 32, F_ / 32), tb, 0, stream>>>(W2, W2T, F_, H_);
  transpose_cast<<<dim3(4 * H_ / 32, 2 * H_ / 32), tb, 0, stream>>>(Wg, WgxT, 2 * H_, 4 * H_);
  transpose_cast<<<dim3(4 * H_ / 32, H_ / 32), tb, 0, stream>>>(Wg + (size_t)(2 * H_) * (4 * H_), WhT, H_, 4 * H_);

  // ---- projections ----
  gemm_bt<<<dim3(H_ / 128, TB_ / 128), 256, 0, stream>>>(xb, WqT, qb, bq, H_, H_, 0.125f, 0);
  gemm_bt<<<dim3(H_ / 128, SB_ / 128), 256, 0, stream>>>(memb, WkT, kb, bk, H_, H_, 1.0f, 0);
  gemm_bt<<<dim3(H_ / 128, SB_ / 128), 256, 0, stream>>>(memb, WvT, vb, bv, H_, H_, 1.0f, 0);

  // ---- attention ----
  attn_kernel<<<dim3(B_ * NH_), 256, 0, stream>>>(qb, kb, vb, src_bias, ctxb);

  // ---- output proj -> xs[:, H:2H] ----
  gemm_bt<<<dim3(H_ / 128, TB_ / 128), 256, 0, stream>>>(ctxb, WoT, xs + H_, bo, H_, 2 * H_, 1.0f, 0);

  // ---- FFN -> xs[:, 0:H] ----
  gemm_bt<<<dim3(F_ / 128, TB_ / 128), 256, 0, stream>>>(xb, W1T, h1, b1, H_, F_, 1.0f, 1);
  gemm_bt<<<dim3(H_ / 128, TB_ / 128), 256, 0, stream>>>(h1, W2T, xs, b2, F_, 2 * H_, 1.0f, 0);

  // ---- gate x-part ----
  gemm_bt<<<dim3(4 * H_ / 128, TB_ / 128), 256, 0, stream>>>(xs, WgxT, gx, bg, 2 * H_, 4 * H_, 1.0f, 0);

  // ---- persistent LSTM ----
  hipMemsetAsync(bar, 0, 256, stream);
  lstm_persistent<<<dim3(64), 256, 0, stream>>>(gx, WhT, hb0, hb1, out, bar);
}

// Round 4
// 2565.771 us; speedup vs baseline: 1.8578x; 1.0370x over previous
//
#include <hip/hip_runtime.h>
#include <cstdint>
#include <cstddef>

// Problem constants
#define T_  256
#define S_  128
#define B_  32
#define H_  1024
#define NH_ 16
#define D_  64
#define F_  4096
#define TB_ (T_*B_)   // 8192
#define SB_ (S_*B_)   // 4096

typedef unsigned short u16;
typedef unsigned int   u32;
typedef unsigned long long u64;
typedef __attribute__((ext_vector_type(8))) short s16x8;   // 8 bf16 (4 VGPRs)
typedef __attribute__((ext_vector_type(4))) float f32x4;

static __device__ __forceinline__ float b2f(u16 u) {
  union { u32 i; float f; } cv; cv.i = ((u32)u) << 16; return cv.f;
}
static __device__ __forceinline__ u16 f2b(float f) {
  union { float f; u32 i; } cv; cv.f = f;
  u32 u = cv.i;
  u32 r = (u + 0x7fffu + ((u >> 16) & 1u)) >> 16;   // RNE
  return (u16)r;
}
static __device__ __forceinline__ float sigm(float x) {
  return 1.0f / (1.0f + __expf(-x));
}
static __device__ __forceinline__ float tanh_fast(float x) {
  float e2 = __expf(2.0f * x);
  return 1.0f - 2.0f / (e2 + 1.0f);    // stable: ->1 for x>>0, ->-1 for x<<0
}

// async global->LDS DMA, 16B per lane; LDS dest = wave-uniform base + lane*16
typedef const __attribute__((address_space(1))) void* gvoidp;
typedef __attribute__((address_space(3))) void* lvoidp;
static __device__ __forceinline__ void gl_lds16(const void* g, void* l) {
  __builtin_amdgcn_global_load_lds((gvoidp)g, (lvoidp)l, 16, 0, 0);
}

// 16B load as two relaxed agent-scope (device-coherent) 8B atomic loads.
static __device__ __forceinline__ s16x8 ld_h16(const u16* p) {
  union { s16x8 v; u64 q[2]; } r;
  u64* q = (u64*)p;
  r.q[0] = __hip_atomic_load(q,     __ATOMIC_RELAXED, __HIP_MEMORY_SCOPE_AGENT);
  r.q[1] = __hip_atomic_load(q + 1, __ATOMIC_RELAXED, __HIP_MEMORY_SCOPE_AGENT);
  return r.v;
}
static __device__ __forceinline__ void st_h2(u16* p, u16 v) {
  __hip_atomic_store(p, v, __ATOMIC_RELAXED, __HIP_MEMORY_SCOPE_AGENT);
}

// ---------------- cast fp32 -> bf16 (vectorized x4) ----------------
__global__ void cast_bf16(const float* __restrict__ in, u16* __restrict__ out, int n4) {
  int i = blockIdx.x * 256 + threadIdx.x;
  if (i < n4) {
    float4 v = reinterpret_cast<const float4*>(in)[i];
    ushort4 o;
    o.x = f2b(v.x); o.y = f2b(v.y); o.z = f2b(v.z); o.w = f2b(v.w);
    reinterpret_cast<ushort4*>(out)[i] = o;
  }
}

// ---------------- transpose + cast: in fp32 [R,C] -> out bf16 [C,R] ----------------
__global__ void transpose_cast(const float* __restrict__ in, u16* __restrict__ out,
                               int R, int C) {
  __shared__ float tile[32][33];
  int c0 = blockIdx.x * 32, r0 = blockIdx.y * 32;
  int tx = threadIdx.x, ty = threadIdx.y;
  #pragma unroll
  for (int k = 0; k < 32; k += 8)
    tile[ty + k][tx] = in[(size_t)(r0 + ty + k) * C + c0 + tx];
  __syncthreads();
  #pragma unroll
  for (int k = 0; k < 32; k += 8)
    out[(size_t)(c0 + ty + k) * R + r0 + tx] = f2b(tile[tx][ty + k]);
}

// ---------------- one-time weight rearrange for the LSTM ----------------
// WhR[bk][w][g][kc][lane][8] <- WhT[g*1024 + bk*16 + (lane&15)][w*256 + kc*32 + (lane>>4)*8 .. +8]
// One thread = one 16B chunk. Dst fully contiguous; src 16B-chunk gather.
__global__ void rearrange_wh(const u16* __restrict__ WhT, u16* __restrict__ WhR) {
  int idx = blockIdx.x * 256 + threadIdx.x;     // 64*4*4*8*64 = 524288 chunks
  int lane = idx & 63;
  int kc = (idx >> 6) & 7;
  int g  = (idx >> 9) & 3;
  int w  = (idx >> 11) & 3;
  int bk = idx >> 13;
  int row = g * H_ + bk * 16 + (lane & 15);
  int col = w * 256 + kc * 32 + (lane >> 4) * 8;
  *(uint4*)&WhR[(size_t)idx * 8] = *(const uint4*)&WhT[(size_t)row * H_ + col];
}

// ---------------- GEMM: Out[M,N] = act((A[M,K] @ Bt[N,K]^T + bias) * scale) ----------------
__global__ __launch_bounds__(256) void gemm_bt(
    const u16* __restrict__ A, const u16* __restrict__ Bt,
    u16* __restrict__ Out, const float* __restrict__ bias,
    int Kdim, int ostride, float scale, int relu)
{
  __shared__ __align__(16) u16 As[128 * 32];
  __shared__ __align__(16) u16 Bs[128 * 32];
  const int tid  = threadIdx.x;
  const int wave = tid >> 6, lane = tid & 63;
  const int quad = lane >> 4, l16 = lane & 15;
  const int bm = blockIdx.y << 7, bn = blockIdx.x << 7;
  const int wm = (wave & 1) << 6, wn = (wave >> 1) << 6;
  f32x4 acc[4][4] = {};

  const int sr = wave * 32 + (lane >> 2);
  const int sc = (lane & 3) * 8;
  const u16* ga = &A [(size_t)(bm + sr) * Kdim + sc];
  const u16* gb = &Bt[(size_t)(bn + sr) * Kdim + sc];
  u16* lA = &As[wave * 1024];
  u16* lB = &Bs[wave * 1024];
  const size_t rowskip = (size_t)16 * Kdim;

  for (int k0 = 0; k0 < Kdim; k0 += 32) {
    gl_lds16(ga + k0,           lA);
    gl_lds16(ga + k0 + rowskip, lA + 512);
    gl_lds16(gb + k0,           lB);
    gl_lds16(gb + k0 + rowskip, lB + 512);
    __syncthreads();
    s16x8 af[4], bf[4];
    #pragma unroll
    for (int mt = 0; mt < 4; mt++)
      af[mt] = *(const s16x8*)&As[(wm + mt * 16 + l16) * 32 + quad * 8];
    #pragma unroll
    for (int nt = 0; nt < 4; nt++)
      bf[nt] = *(const s16x8*)&Bs[(wn + nt * 16 + l16) * 32 + quad * 8];
    #pragma unroll
    for (int mt = 0; mt < 4; mt++)
      #pragma unroll
      for (int nt = 0; nt < 4; nt++)
        acc[mt][nt] = __builtin_amdgcn_mfma_f32_16x16x32_bf16(af[mt], bf[nt], acc[mt][nt], 0, 0, 0);
    __syncthreads();
  }

  #pragma unroll
  for (int mt = 0; mt < 4; mt++) {
    #pragma unroll
    for (int nt = 0; nt < 4; nt++) {
      const int col = bn + wn + nt * 16 + l16;
      const float bv = bias[col];
      #pragma unroll
      for (int r = 0; r < 4; r++) {
        const int row = bm + wm + mt * 16 + quad * 4 + r;
        float vv = (acc[mt][nt][r] + bv) * scale;
        if (relu) vv = fmaxf(vv, 0.0f);
        Out[(size_t)row * ostride + col] = f2b(vv);
      }
    }
  }
}

// ---------------- attention: one block per (b, head); thread t owns query t ----------------
__global__ __launch_bounds__(256) void attn_kernel(
    const u16* __restrict__ q, const u16* __restrict__ k, const u16* __restrict__ v,
    const float* __restrict__ src_bias, u16* __restrict__ ctx)
{
  __shared__ u16 ks[S_ * D_];
  __shared__ u16 vs[S_ * D_];
  const int b  = blockIdx.x >> 4;
  const int nh = blockIdx.x & 15;
  const int tid = threadIdx.x;

  for (int i = tid; i < (S_ * D_) / 8; i += 256) {
    int s = i >> 3, c = (i & 7) * 8;
    *(uint4*)&ks[s * D_ + c] = *(const uint4*)&k[((size_t)(s * B_ + b)) * H_ + nh * D_ + c];
    *(uint4*)&vs[s * D_ + c] = *(const uint4*)&v[((size_t)(s * B_ + b)) * H_ + nh * D_ + c];
  }
  __syncthreads();

  const int t = tid;
  float qf[D_];
  const u16* qp = &q[((size_t)(t * B_ + b)) * H_ + nh * D_];
  #pragma unroll
  for (int c8 = 0; c8 < D_; c8 += 8) {
    uint4 qv = *(const uint4*)&qp[c8];
    const u16* pu = (const u16*)&qv;
    #pragma unroll
    for (int j = 0; j < 8; j++) qf[c8 + j] = b2f(pu[j]);
  }
  const float* bias = src_bias + b * S_;

  float m = -1e30f, l = 0.0f;
  for (int s = 0; s < S_; s++) {
    float dot = 0.0f;
    #pragma unroll
    for (int d = 0; d < D_; d++) dot += qf[d] * b2f(ks[s * D_ + d]);
    dot += bias[s];
    float nm = fmaxf(m, dot);
    l = l * __expf(m - nm) + __expf(dot - nm);
    m = nm;
  }
  float of[D_] = {};
  const float inv = 1.0f / l;
  for (int s = 0; s < S_; s++) {
    float dot = 0.0f;
    #pragma unroll
    for (int d = 0; d < D_; d++) dot += qf[d] * b2f(ks[s * D_ + d]);
    dot += bias[s];
    float w = __expf(dot - m) * inv;
    #pragma unroll
    for (int d = 0; d < D_; d++) of[d] += w * b2f(vs[s * D_ + d]);
  }
  u16* op = &ctx[((size_t)(t * B_ + b)) * H_ + nh * D_];
  #pragma unroll
  for (int c8 = 0; c8 < D_; c8 += 8) {
    u16 tmp[8];
    #pragma unroll
    for (int j = 0; j < 8; j++) tmp[j] = f2b(of[c8 + j]);
    *(uint4*)&op[c8] = *(const uint4*)tmp;
  }
}

// ---------------- persistent LSTM v3 ----------------
// 64 blocks x 256 thr, 1/CU (grid <= CUs). Block bk owns H-cols [bk*16,+16).
// Weights: gates 0-2 in LDS (96 KB, lane-contiguous conflict-free), gate 3 in
// 32 pinned VGPRs. K-split: wave w owns k in [w*256,+256) -> h read once/block.
// Sync: distributed flags (one per block, plain relaxed sc1 stores, no RMW);
// wave w polls only its 16 producer blocks via one 64-lane __all.
__global__ __launch_bounds__(256, 1) void lstm_persistent(
    const u16* __restrict__ g_x, const u16* __restrict__ WhR,
    u16* __restrict__ hb0, u16* __restrict__ hb1,
    float* __restrict__ out, int* flag)
{
  __shared__ __align__(16) u16 Wl[4][3 * 8 * 64 * 8];  // [wave][(g*8+kc)*64+lane chunks] 96 KB
  __shared__ float P[4][4][32][17];                     // [k-wave][gate][batch][col] 34.8 KB
  const int bk = blockIdx.x, tid = threadIdx.x;
  const int wave = tid >> 6, lane = tid & 63;
  const int quad = lane >> 4, l16 = lane & 15;

  // ---- one-time weight staging ----
  const u16* wsrc = WhR + ((size_t)(bk * 4 + wave) * 4 * 8 * 64) * 8;
  for (int i = lane; i < 3 * 8 * 64; i += 64)
    *(uint4*)&Wl[wave][i * 8] = *(const uint4*)&wsrc[(size_t)i * 8];
  s16x8 wo[8];                       // gate-3 weights, registers
  #pragma unroll
  for (int kc = 0; kc < 8; kc++)
    wo[kc] = *(const s16x8*)&wsrc[((size_t)(3 * 8 + kc) * 64 + lane) * 8];
  __syncthreads();

  const int pb = tid >> 4;        // batch 0..15 (+16 for second output)
  const int pc = tid & 15;        // local col
  const int col = bk * 16 + pc;
  float creg[2] = {0.0f, 0.0f};

  // g_x prefetch for t=0
  float gxp[2][4];
  #pragma unroll
  for (int ii = 0; ii < 2; ii++)
    #pragma unroll
    for (int g = 0; g < 4; g++)
      gxp[ii][g] = b2f(g_x[((size_t)(pb + ii * 16)) * (4 * H_) + g * H_ + col]);

  for (int t = 0; t < T_; t++) {
    const u16* hin = (t & 1) ? hb0 : hb1;
    u16* hout      = (t & 1) ? hb1 : hb0;

    if (t > 0) {
      // ---- wait for this wave's 16 producer blocks ----
      const int src = (wave << 4) + l16;    // 4-way duplicated across quads: one cacheline
      int f;
      do { f = __hip_atomic_load(&flag[src], __ATOMIC_RELAXED, __HIP_MEMORY_SCOPE_AGENT); }
      while (!__all(f >= t));
      asm volatile("" ::: "memory");        // no hoisting h loads above the poll

      // ---- gate GEMM, K-split ----
      f32x4 acc[4][2] = {};
      const u16* hbase = hin + wave * 256 + quad * 8;
      #pragma unroll
      for (int kc = 0; kc < 8; kc++) {
        s16x8 a0 = ld_h16(&hbase[(size_t)l16 * H_ + kc * 32]);
        s16x8 a1 = ld_h16(&hbase[(size_t)(16 + l16) * H_ + kc * 32]);
        #pragma unroll
        for (int g = 0; g < 3; g++) {
          s16x8 wf = *(const s16x8*)&Wl[wave][((g * 8 + kc) * 64 + lane) * 8];
          acc[g][0] = __builtin_amdgcn_mfma_f32_16x16x32_bf16(a0, wf, acc[g][0], 0, 0, 0);
          acc[g][1] = __builtin_amdgcn_mfma_f32_16x16x32_bf16(a1, wf, acc[g][1], 0, 0, 0);
        }
        acc[3][0] = __builtin_amdgcn_mfma_f32_16x16x32_bf16(a0, wo[kc], acc[3][0], 0, 0, 0);
        acc[3][1] = __builtin_amdgcn_mfma_f32_16x16x32_bf16(a1, wo[kc], acc[3][1], 0, 0, 0);
      }
      #pragma unroll
      for (int g = 0; g < 4; g++)
        #pragma unroll
        for (int mt = 0; mt < 2; mt++)
          #pragma unroll
          for (int r = 0; r < 4; r++)
            P[wave][g][mt * 16 + quad * 4 + r][l16] = acc[g][mt][r];
    }
    __syncthreads();

    // ---- reduce partials + pointwise ----
    float hn[2], cn[2];
    #pragma unroll
    for (int ii = 0; ii < 2; ii++) {
      const int b_ = pb + ii * 16;
      float gs[4];
      #pragma unroll
      for (int g = 0; g < 4; g++) {
        float s = gxp[ii][g];
        if (t > 0) s += P[0][g][b_][pc] + P[1][g][b_][pc] + P[2][g][b_][pc] + P[3][g][b_][pc];
        gs[g] = s;
      }
      const float iv = sigm(gs[0]);
      const float jv = tanh_fast(gs[1]);
      const float fv = sigm(gs[2]);
      const float ov = sigm(gs[3]);
      cn[ii] = fv * creg[ii] + iv * jv;
      hn[ii] = ov * cn[ii];
      creg[ii] = cn[ii];
      st_h2(&hout[(size_t)b_ * H_ + col], f2b(hn[ii]));   // h publish (sc1)
    }

    // ---- publish flag ASAP (critical path), then do deferred work ----
    if (t < T_ - 1) {
      asm volatile("s_waitcnt vmcnt(0)" ::: "memory");   // h at coherence point
      __syncthreads();                                   // whole block published
      if (tid == 0)
        __hip_atomic_store(&flag[bk], t + 1, __ATOMIC_RELAXED, __HIP_MEMORY_SCOPE_AGENT);
    }

    // deferred: fp32 output stores + next g_x prefetch (off critical path)
    #pragma unroll
    for (int ii = 0; ii < 2; ii++) {
      const int b_ = pb + ii * 16;
      out[(size_t)t * (B_ * H_) + b_ * H_ + col] = hn[ii];
      if (t == T_ - 1) {
        out[(size_t)T_ * B_ * H_ + b_ * H_ + col] = cn[ii];              // c_f
        out[(size_t)T_ * B_ * H_ + B_ * H_ + b_ * H_ + col] = hn[ii];    // h_f
      }
    }
    if (t < T_ - 1) {
      #pragma unroll
      for (int ii = 0; ii < 2; ii++)
        #pragma unroll
        for (int g = 0; g < 4; g++)
          gxp[ii][g] = b2f(g_x[((size_t)(t + 1) * B_ + pb + ii * 16) * (4 * H_) + g * H_ + col]);
    }
  }
}

extern "C" void kernel_launch(void* const* d_in, const int* in_sizes, int n_in,
                              void* d_out, int out_size, void* d_ws, size_t ws_size,
                              hipStream_t stream)
{
  const float* x        = (const float*)d_in[0];
  const float* src_bias = (const float*)d_in[1];
  const float* mem      = (const float*)d_in[3];
  const float* Wq = (const float*)d_in[4];  const float* bq = (const float*)d_in[5];
  const float* Wk = (const float*)d_in[6];  const float* bk = (const float*)d_in[7];
  const float* Wv = (const float*)d_in[8];  const float* bv = (const float*)d_in[9];
  const float* Wo = (const float*)d_in[10]; const float* bo = (const float*)d_in[11];
  const float* W1 = (const float*)d_in[12]; const float* b1 = (const float*)d_in[13];
  const float* W2 = (const float*)d_in[14]; const float* b2 = (const float*)d_in[15];
  const float* Wg = (const float*)d_in[16]; const float* bg = (const float*)d_in[17];
  float* out = (float*)d_out;

  char* p = (char*)d_ws;
  u16* xb   = (u16*)p; p += (size_t)TB_ * H_ * 2;
  u16* memb = (u16*)p; p += (size_t)SB_ * H_ * 2;
  u16* WqT  = (u16*)p; p += (size_t)H_ * H_ * 2;
  u16* WkT  = (u16*)p; p += (size_t)H_ * H_ * 2;
  u16* WvT  = (u16*)p; p += (size_t)H_ * H_ * 2;
  u16* WoT  = (u16*)p; p += (size_t)H_ * H_ * 2;
  u16* W1T  = (u16*)p; p += (size_t)F_ * H_ * 2;
  u16* W2T  = (u16*)p; p += (size_t)H_ * F_ * 2;
  u16* WgxT = (u16*)p; p += (size_t)(4 * H_) * (2 * H_) * 2;
  u16* WhT  = (u16*)p; p += (size_t)(4 * H_) * H_ * 2;
  u16* WhR  = (u16*)p; p += (size_t)(4 * H_) * H_ * 2;   // rearranged for LSTM
  u16* qb   = (u16*)p; p += (size_t)TB_ * H_ * 2;
  u16* kb   = (u16*)p; p += (size_t)SB_ * H_ * 2;
  u16* vb   = (u16*)p; p += (size_t)SB_ * H_ * 2;
  u16* ctxb = (u16*)p; p += (size_t)TB_ * H_ * 2;
  u16* xs   = (u16*)p; p += (size_t)TB_ * (2 * H_) * 2;
  u16* h1   = (u16*)p; p += (size_t)TB_ * F_ * 2;    // FFN hidden; reused as g_x
  u16* hb0  = (u16*)p; p += (size_t)B_ * H_ * 2;
  u16* hb1  = (u16*)p; p += (size_t)B_ * H_ * 2;
  int* flag = (int*)p; p += 256;
  u16* gx   = h1;

  // ---- casts ----
  cast_bf16<<<dim3((TB_ * H_ / 4) / 256), dim3(256), 0, stream>>>(x, xb, TB_ * H_ / 4);
  cast_bf16<<<dim3((SB_ * H_ / 4) / 256), dim3(256), 0, stream>>>(mem, memb, SB_ * H_ / 4);

  // ---- weight transposes ----
  dim3 tb(32, 8);
  transpose_cast<<<dim3(H_ / 32, H_ / 32), tb, 0, stream>>>(Wq, WqT, H_, H_);
  transpose_cast<<<dim3(H_ / 32, H_ / 32), tb, 0, stream>>>(Wk, WkT, H_, H_);
  transpose_cast<<<dim3(H_ / 32, H_ / 32), tb, 0, stream>>>(Wv, WvT, H_, H_);
  transpose_cast<<<dim3(H_ / 32, H_ / 32), tb, 0, stream>>>(Wo, WoT, H_, H_);
  transpose_cast<<<dim3(F_ / 32, H_ / 32), tb, 0, stream>>>(W1, W1T, H_, F_);
  transpose_cast<<<dim3(H_ / 32, F_ / 32), tb, 0, stream>>>(W2, W2T, F_, H_);
  transpose_cast<<<dim3(4 * H_ / 32, 2 * H_ / 32), tb, 0, stream>>>(Wg, WgxT, 2 * H_, 4 * H_);
  transpose_cast<<<dim3(4 * H_ / 32, H_ / 32), tb, 0, stream>>>(Wg + (size_t)(2 * H_) * (4 * H_), WhT, H_, 4 * H_);
  rearrange_wh<<<dim3(2048), 256, 0, stream>>>(WhT, WhR);

  // ---- projections ----
  gemm_bt<<<dim3(H_ / 128, TB_ / 128), 256, 0, stream>>>(xb, WqT, qb, bq, H_, H_, 0.125f, 0);
  gemm_bt<<<dim3(H_ / 128, SB_ / 128), 256, 0, stream>>>(memb, WkT, kb, bk, H_, H_, 1.0f, 0);
  gemm_bt<<<dim3(H_ / 128, SB_ / 128), 256, 0, stream>>>(memb, WvT, vb, bv, H_, H_, 1.0f, 0);

  // ---- attention ----
  attn_kernel<<<dim3(B_ * NH_), 256, 0, stream>>>(qb, kb, vb, src_bias, ctxb);

  // ---- output proj -> xs[:, H:2H] ----
  gemm_bt<<<dim3(H_ / 128, TB_ / 128), 256, 0, stream>>>(ctxb, WoT, xs + H_, bo, H_, 2 * H_, 1.0f, 0);

  // ---- FFN -> xs[:, 0:H] ----
  gemm_bt<<<dim3(F_ / 128, TB_ / 128), 256, 0, stream>>>(xb, W1T, h1, b1, H_, F_, 1.0f, 1);
  gemm_bt<<<dim3(H_ / 128, TB_ / 128), 256, 0, stream>>>(h1, W2T, xs, b2, F_, 2 * H_, 1.0f, 0);

  // ---- gate x-part ----
  gemm_bt<<<dim3(4 * H_ / 128, TB_ / 128), 256, 0, stream>>>(xs, WgxT, gx, bg, 2 * H_, 4 * H_, 1.0f, 0);

  // ---- persistent LSTM ----
  hipMemsetAsync(flag, 0, 256, stream);
  lstm_persistent<<<dim3(64), 256, 0, stream>>>(gx, WhR, hb0, hb1, out, flag);
}

// Round 5
// 2232.719 us; speedup vs baseline: 2.1349x; 1.1492x over previous
//
#include <hip/hip_runtime.h>
#include <cstdint>
#include <cstddef>

// Problem constants
#define T_  256
#define S_  128
#define B_  32
#define H_  1024
#define NH_ 16
#define D_  64
#define F_  4096
#define TB_ (T_*B_)   // 8192
#define SB_ (S_*B_)   // 4096

typedef unsigned short u16;
typedef unsigned int   u32;
typedef unsigned long long u64;
typedef __attribute__((ext_vector_type(8))) short s16x8;   // 8 bf16 (4 VGPRs)
typedef __attribute__((ext_vector_type(4))) float f32x4;
typedef __attribute__((ext_vector_type(4))) u32  u32x4;

static __device__ __forceinline__ float b2f(u16 u) {
  union { u32 i; float f; } cv; cv.i = ((u32)u) << 16; return cv.f;
}
static __device__ __forceinline__ u16 f2b(float f) {
  union { float f; u32 i; } cv; cv.f = f;
  u32 u = cv.i;
  u32 r = (u + 0x7fffu + ((u >> 16) & 1u)) >> 16;   // RNE
  return (u16)r;
}
static __device__ __forceinline__ float sigm(float x) {
  return 1.0f / (1.0f + __expf(-x));
}
static __device__ __forceinline__ float tanh_fast(float x) {
  float e2 = __expf(2.0f * x);
  return 1.0f - 2.0f / (e2 + 1.0f);
}

// async global->LDS DMA, 16B per lane
typedef const __attribute__((address_space(1))) void* gvoidp;
typedef __attribute__((address_space(3))) void* lvoidp;
static __device__ __forceinline__ void gl_lds16(const void* g, void* l) {
  __builtin_amdgcn_global_load_lds((gvoidp)g, (lvoidp)l, 16, 0, 0);
}

static __device__ __forceinline__ bool fresh1(const u32x4 q, u32 st) {
  return ((q[0] >> 16) == st) & ((q[1] >> 16) == st) &
         ((q[2] >> 16) == st) & ((q[3] >> 16) == st);
}
static __device__ __forceinline__ s16x8 pack2(const u32x4 qa, const u32x4 qb) {
  s16x8 r;
  r[0] = (short)qa[0]; r[1] = (short)qa[1]; r[2] = (short)qa[2]; r[3] = (short)qa[3];
  r[4] = (short)qb[0]; r[5] = (short)qb[1]; r[6] = (short)qb[2]; r[7] = (short)qb[3];
  return r;
}

// ---------------- cast fp32 -> bf16 ----------------
__global__ void cast_bf16(const float* __restrict__ in, u16* __restrict__ out, int n4) {
  int i = blockIdx.x * 256 + threadIdx.x;
  if (i < n4) {
    float4 v = reinterpret_cast<const float4*>(in)[i];
    ushort4 o;
    o.x = f2b(v.x); o.y = f2b(v.y); o.z = f2b(v.z); o.w = f2b(v.w);
    reinterpret_cast<ushort4*>(out)[i] = o;
  }
}

// ---------------- transpose + cast ----------------
__global__ void transpose_cast(const float* __restrict__ in, u16* __restrict__ out,
                               int R, int C) {
  __shared__ float tile[32][33];
  int c0 = blockIdx.x * 32, r0 = blockIdx.y * 32;
  int tx = threadIdx.x, ty = threadIdx.y;
  #pragma unroll
  for (int k = 0; k < 32; k += 8)
    tile[ty + k][tx] = in[(size_t)(r0 + ty + k) * C + c0 + tx];
  __syncthreads();
  #pragma unroll
  for (int k = 0; k < 32; k += 8)
    out[(size_t)(c0 + ty + k) * R + r0 + tx] = f2b(tile[tx][ty + k]);
}

// ---------------- one-time weight rearrange for the LSTM ----------------
__global__ void rearrange_wh(const u16* __restrict__ WhT, u16* __restrict__ WhR) {
  int idx = blockIdx.x * 256 + threadIdx.x;
  int lane = idx & 63;
  int kc = (idx >> 6) & 7;
  int g  = (idx >> 9) & 3;
  int w  = (idx >> 11) & 3;
  int bk = idx >> 13;
  int row = g * H_ + bk * 16 + (lane & 15);
  int col = w * 256 + kc * 32 + (lane >> 4) * 8;
  *(uint4*)&WhR[(size_t)idx * 8] = *(const uint4*)&WhT[(size_t)row * H_ + col];
}

// ---------------- GEMM (m97 structure) ----------------
__global__ __launch_bounds__(256) void gemm_bt(
    const u16* __restrict__ A, const u16* __restrict__ Bt,
    u16* __restrict__ Out, const float* __restrict__ bias,
    int Kdim, int ostride, float scale, int relu)
{
  __shared__ __align__(16) u16 As[128 * 32];
  __shared__ __align__(16) u16 Bs[128 * 32];
  const int tid  = threadIdx.x;
  const int wave = tid >> 6, lane = tid & 63;
  const int quad = lane >> 4, l16 = lane & 15;
  const int bm = blockIdx.y << 7, bn = blockIdx.x << 7;
  const int wm = (wave & 1) << 6, wn = (wave >> 1) << 6;
  f32x4 acc[4][4] = {};

  const int sr = wave * 32 + (lane >> 2);
  const int sc = (lane & 3) * 8;
  const u16* ga = &A [(size_t)(bm + sr) * Kdim + sc];
  const u16* gb = &Bt[(size_t)(bn + sr) * Kdim + sc];
  u16* lA = &As[wave * 1024];
  u16* lB = &Bs[wave * 1024];
  const size_t rowskip = (size_t)16 * Kdim;

  for (int k0 = 0; k0 < Kdim; k0 += 32) {
    gl_lds16(ga + k0,           lA);
    gl_lds16(ga + k0 + rowskip, lA + 512);
    gl_lds16(gb + k0,           lB);
    gl_lds16(gb + k0 + rowskip, lB + 512);
    __syncthreads();
    s16x8 af[4], bf[4];
    #pragma unroll
    for (int mt = 0; mt < 4; mt++)
      af[mt] = *(const s16x8*)&As[(wm + mt * 16 + l16) * 32 + quad * 8];
    #pragma unroll
    for (int nt = 0; nt < 4; nt++)
      bf[nt] = *(const s16x8*)&Bs[(wn + nt * 16 + l16) * 32 + quad * 8];
    #pragma unroll
    for (int mt = 0; mt < 4; mt++)
      #pragma unroll
      for (int nt = 0; nt < 4; nt++)
        acc[mt][nt] = __builtin_amdgcn_mfma_f32_16x16x32_bf16(af[mt], bf[nt], acc[mt][nt], 0, 0, 0);
    __syncthreads();
  }

  #pragma unroll
  for (int mt = 0; mt < 4; mt++) {
    #pragma unroll
    for (int nt = 0; nt < 4; nt++) {
      const int col = bn + wn + nt * 16 + l16;
      const float bv = bias[col];
      #pragma unroll
      for (int r = 0; r < 4; r++) {
        const int row = bm + wm + mt * 16 + quad * 4 + r;
        float vv = (acc[mt][nt][r] + bv) * scale;
        if (relu) vv = fmaxf(vv, 0.0f);
        Out[(size_t)row * ostride + col] = f2b(vv);
      }
    }
  }
}

// ---------------- attention ----------------
__global__ __launch_bounds__(256) void attn_kernel(
    const u16* __restrict__ q, const u16* __restrict__ k, const u16* __restrict__ v,
    const float* __restrict__ src_bias, u16* __restrict__ ctx)
{
  __shared__ u16 ks[S_ * D_];
  __shared__ u16 vs[S_ * D_];
  const int b  = blockIdx.x >> 4;
  const int nh = blockIdx.x & 15;
  const int tid = threadIdx.x;

  for (int i = tid; i < (S_ * D_) / 8; i += 256) {
    int s = i >> 3, c = (i & 7) * 8;
    *(uint4*)&ks[s * D_ + c] = *(const uint4*)&k[((size_t)(s * B_ + b)) * H_ + nh * D_ + c];
    *(uint4*)&vs[s * D_ + c] = *(const uint4*)&v[((size_t)(s * B_ + b)) * H_ + nh * D_ + c];
  }
  __syncthreads();

  const int t = tid;
  float qf[D_];
  const u16* qp = &q[((size_t)(t * B_ + b)) * H_ + nh * D_];
  #pragma unroll
  for (int c8 = 0; c8 < D_; c8 += 8) {
    uint4 qv = *(const uint4*)&qp[c8];
    const u16* pu = (const u16*)&qv;
    #pragma unroll
    for (int j = 0; j < 8; j++) qf[c8 + j] = b2f(pu[j]);
  }
  const float* bias = src_bias + b * S_;

  float m = -1e30f, l = 0.0f;
  for (int s = 0; s < S_; s++) {
    float dot = 0.0f;
    #pragma unroll
    for (int d = 0; d < D_; d++) dot += qf[d] * b2f(ks[s * D_ + d]);
    dot += bias[s];
    float nm = fmaxf(m, dot);
    l = l * __expf(m - nm) + __expf(dot - nm);
    m = nm;
  }
  float of[D_] = {};
  const float inv = 1.0f / l;
  for (int s = 0; s < S_; s++) {
    float dot = 0.0f;
    #pragma unroll
    for (int d = 0; d < D_; d++) dot += qf[d] * b2f(ks[s * D_ + d]);
    dot += bias[s];
    float w = __expf(dot - m) * inv;
    #pragma unroll
    for (int d = 0; d < D_; d++) of[d] += w * b2f(vs[s * D_ + d]);
  }
  u16* op = &ctx[((size_t)(t * B_ + b)) * H_ + nh * D_];
  #pragma unroll
  for (int c8 = 0; c8 < D_; c8 += 8) {
    u16 tmp[8];
    #pragma unroll
    for (int j = 0; j < 8; j++) tmp[j] = f2b(of[c8 + j]);
    *(uint4*)&op[c8] = *(const uint4*)tmp;
  }
}

// ---------------- persistent LSTM v4: stamped-h dataflow, no barrier ----------------
// h element = u32 dword: (stamp << 16) | bf16(h). Dword stores are indivisible,
// so data carries its own arrival flag: no producer drain, no flag, no grid sync.
// Double-buffered by step parity (overwrite-safe: a block reaches step t+1 only
// after every block consumed h(t-1)). Poisoned stamp 0xAAAA never matches t.
// Layout: hseq[par][cb][b][c] dwords, cb = h-col/16 (block that owns it).
#define ISSUE_BANK(Q0,Q1,Q2,Q3,KC)                                                  \
  { const u32* bp_ = hr + ((size_t)(wave * 16 + (KC) * 2 + (quad >> 1))) * 512 +    \
                     (quad & 1) * 8;                                                \
    const u32* p0_ = bp_ + l16 * 16;                                                \
    const u32* p1_ = bp_ + (16 + l16) * 16;                                         \
    asm volatile("global_load_dwordx4 %0, %1, off sc0 sc1" : "=v"(Q0) : "v"(p0_) : "memory");     \
    asm volatile("global_load_dwordx4 %0, %1, off sc0 sc1" : "=v"(Q1) : "v"(p0_ + 4) : "memory"); \
    asm volatile("global_load_dwordx4 %0, %1, off sc0 sc1" : "=v"(Q2) : "v"(p1_) : "memory");     \
    asm volatile("global_load_dwordx4 %0, %1, off sc0 sc1" : "=v"(Q3) : "v"(p1_ + 4) : "memory"); }
#define WAIT4 asm volatile("s_waitcnt vmcnt(4)" ::: "memory")
#define WAIT0 asm volatile("s_waitcnt vmcnt(0)" ::: "memory")
#define POLL_BANK(Q0,Q1,Q2,Q3,KC)                                       \
  { bool ok_ = fresh1(Q0, st) & fresh1(Q1, st) & fresh1(Q2, st) & fresh1(Q3, st); \
    while (!__all(ok_)) {                                               \
      ISSUE_BANK(Q0, Q1, Q2, Q3, KC); WAIT0;                            \
      ok_ = fresh1(Q0, st) & fresh1(Q1, st) & fresh1(Q2, st) & fresh1(Q3, st); } }
#define DO_MFMA(A0,A1,KC)                                                           \
  { _Pragma("unroll") for (int g_ = 0; g_ < 3; g_++) {                              \
      s16x8 wf_ = *(const s16x8*)&Wl[wave][((g_ * 8 + (KC)) * 64 + lane) * 8];      \
      acc[g_][0] = __builtin_amdgcn_mfma_f32_16x16x32_bf16(A0, wf_, acc[g_][0], 0, 0, 0); \
      acc[g_][1] = __builtin_amdgcn_mfma_f32_16x16x32_bf16(A1, wf_, acc[g_][1], 0, 0, 0); } \
    acc[3][0] = __builtin_amdgcn_mfma_f32_16x16x32_bf16(A0, wo[KC], acc[3][0], 0, 0, 0);  \
    acc[3][1] = __builtin_amdgcn_mfma_f32_16x16x32_bf16(A1, wo[KC], acc[3][1], 0, 0, 0); }

__global__ __launch_bounds__(256, 1) void lstm_persistent(
    const u16* __restrict__ g_x, const u16* __restrict__ WhR,
    u32* __restrict__ hseq, float* __restrict__ out)
{
  __shared__ __align__(16) u16 Wl[4][3 * 8 * 64 * 8];  // gates 0-2: 96 KB
  __shared__ float P[4][4][32][17];                     // partials: 34.8 KB
  const int bk = blockIdx.x, tid = threadIdx.x;
  const int wave = tid >> 6, lane = tid & 63;
  const int quad = lane >> 4, l16 = lane & 15;

  // one-time weight staging
  const u16* wsrc = WhR + ((size_t)(bk * 4 + wave) * 4 * 8 * 64) * 8;
  for (int i = lane; i < 3 * 8 * 64; i += 64)
    *(uint4*)&Wl[wave][i * 8] = *(const uint4*)&wsrc[(size_t)i * 8];
  s16x8 wo[8];                       // gate-3 weights in registers
  #pragma unroll
  for (int kc = 0; kc < 8; kc++)
    wo[kc] = *(const s16x8*)&wsrc[((size_t)(3 * 8 + kc) * 64 + lane) * 8];
  __syncthreads();

  const int pb = tid >> 4, pc = tid & 15;
  const int col = bk * 16 + pc;
  float creg[2] = {0.0f, 0.0f};

  float gxp[2][4];
  #pragma unroll
  for (int ii = 0; ii < 2; ii++)
    #pragma unroll
    for (int g = 0; g < 4; g++)
      gxp[ii][g] = b2f(g_x[((size_t)(pb + ii * 16)) * (4 * H_) + g * H_ + col]);

  for (int t = 0; t < T_; t++) {
    if (t > 0) {
      const u32 st = (u32)t;                       // h(t-1) carries stamp t
      const u32* hr = hseq + ((t & 1) ^ 1) * 32768;
      f32x4 acc[4][2] = {};
      u32x4 bA[4], bB[4];
      ISSUE_BANK(bA[0], bA[1], bA[2], bA[3], 0);
      #pragma unroll
      for (int k2 = 0; k2 < 4; k2++) {
        ISSUE_BANK(bB[0], bB[1], bB[2], bB[3], 2 * k2 + 1);
        WAIT4;
        POLL_BANK(bA[0], bA[1], bA[2], bA[3], 2 * k2);
        { s16x8 a0 = pack2(bA[0], bA[1]), a1 = pack2(bA[2], bA[3]);
          DO_MFMA(a0, a1, 2 * k2); }
        if (k2 < 3) { ISSUE_BANK(bA[0], bA[1], bA[2], bA[3], 2 * k2 + 2); WAIT4; }
        else WAIT0;
        POLL_BANK(bB[0], bB[1], bB[2], bB[3], 2 * k2 + 1);
        { s16x8 a0 = pack2(bB[0], bB[1]), a1 = pack2(bB[2], bB[3]);
          DO_MFMA(a0, a1, 2 * k2 + 1); }
      }
      #pragma unroll
      for (int g = 0; g < 4; g++)
        #pragma unroll
        for (int mt = 0; mt < 2; mt++)
          #pragma unroll
          for (int r = 0; r < 4; r++)
            P[wave][g][mt * 16 + quad * 4 + r][l16] = acc[g][mt][r];
    }
    __syncthreads();

    // reduce partials into gate sums (register-only after this)
    float gs[2][4];
    #pragma unroll
    for (int ii = 0; ii < 2; ii++) {
      const int b_ = pb + ii * 16;
      #pragma unroll
      for (int g = 0; g < 4; g++) {
        float s = gxp[ii][g];
        if (t > 0) s += P[0][g][b_][pc] + P[1][g][b_][pc] + P[2][g][b_][pc] + P[3][g][b_][pc];
        gs[ii][g] = s;
      }
    }
    __syncthreads();   // P consumed; next step may overwrite

    // pointwise + stamped h publish (the ONLY synchronization: the data itself)
    u32* hw = hseq + (t & 1) * 32768;
    float hn[2], cn[2];
    #pragma unroll
    for (int ii = 0; ii < 2; ii++) {
      const int b_ = pb + ii * 16;
      const float iv = sigm(gs[ii][0]);
      const float jv = tanh_fast(gs[ii][1]);
      const float fv = sigm(gs[ii][2]);
      const float ov = sigm(gs[ii][3]);
      cn[ii] = fv * creg[ii] + iv * jv;
      hn[ii] = ov * cn[ii];
      creg[ii] = cn[ii];
      u32 dw = ((u32)(t + 1) << 16) | (u32)f2b(hn[ii]);
      __hip_atomic_store(&hw[(size_t)bk * 512 + b_ * 16 + pc], dw,
                         __ATOMIC_RELAXED, __HIP_MEMORY_SCOPE_AGENT);
    }

    // deferred: fp32 outputs + next g_x prefetch (off critical path)
    #pragma unroll
    for (int ii = 0; ii < 2; ii++) {
      const int b_ = pb + ii * 16;
      out[(size_t)t * (B_ * H_) + b_ * H_ + col] = hn[ii];
      if (t == T_ - 1) {
        out[(size_t)T_ * B_ * H_ + b_ * H_ + col] = cn[ii];              // c_f
        out[(size_t)T_ * B_ * H_ + B_ * H_ + b_ * H_ + col] = hn[ii];    // h_f
      }
    }
    if (t < T_ - 1) {
      #pragma unroll
      for (int ii = 0; ii < 2; ii++)
        #pragma unroll
        for (int g = 0; g < 4; g++)
          gxp[ii][g] = b2f(g_x[((size_t)(t + 1) * B_ + pb + ii * 16) * (4 * H_) + g * H_ + col]);
    }
  }
}

extern "C" void kernel_launch(void* const* d_in, const int* in_sizes, int n_in,
                              void* d_out, int out_size, void* d_ws, size_t ws_size,
                              hipStream_t stream)
{
  const float* x        = (const float*)d_in[0];
  const float* src_bias = (const float*)d_in[1];
  const float* mem      = (const float*)d_in[3];
  const float* Wq = (const float*)d_in[4];  const float* bq = (const float*)d_in[5];
  const float* Wk = (const float*)d_in[6];  const float* bk = (const float*)d_in[7];
  const float* Wv = (const float*)d_in[8];  const float* bv = (const float*)d_in[9];
  const float* Wo = (const float*)d_in[10]; const float* bo = (const float*)d_in[11];
  const float* W1 = (const float*)d_in[12]; const float* b1 = (const float*)d_in[13];
  const float* W2 = (const float*)d_in[14]; const float* b2 = (const float*)d_in[15];
  const float* Wg = (const float*)d_in[16]; const float* bg = (const float*)d_in[17];
  float* out = (float*)d_out;

  char* p = (char*)d_ws;
  u16* xb   = (u16*)p; p += (size_t)TB_ * H_ * 2;
  u16* memb = (u16*)p; p += (size_t)SB_ * H_ * 2;
  u16* WqT  = (u16*)p; p += (size_t)H_ * H_ * 2;
  u16* WkT  = (u16*)p; p += (size_t)H_ * H_ * 2;
  u16* WvT  = (u16*)p; p += (size_t)H_ * H_ * 2;
  u16* WoT  = (u16*)p; p += (size_t)H_ * H_ * 2;
  u16* W1T  = (u16*)p; p += (size_t)F_ * H_ * 2;
  u16* W2T  = (u16*)p; p += (size_t)H_ * F_ * 2;
  u16* WgxT = (u16*)p; p += (size_t)(4 * H_) * (2 * H_) * 2;
  u16* WhT  = (u16*)p; p += (size_t)(4 * H_) * H_ * 2;
  u16* WhR  = (u16*)p; p += (size_t)(4 * H_) * H_ * 2;
  u16* qb   = (u16*)p; p += (size_t)TB_ * H_ * 2;
  u16* kb   = (u16*)p; p += (size_t)SB_ * H_ * 2;
  u16* vb   = (u16*)p; p += (size_t)SB_ * H_ * 2;
  u16* ctxb = (u16*)p; p += (size_t)TB_ * H_ * 2;
  u16* xs   = (u16*)p; p += (size_t)TB_ * (2 * H_) * 2;
  u16* h1   = (u16*)p; p += (size_t)TB_ * F_ * 2;    // FFN hidden; reused as g_x
  u32* hseq = (u32*)p; p += (size_t)2 * 32768 * 4;   // stamped h, double-buffered
  u16* gx   = h1;

  // ---- casts ----
  cast_bf16<<<dim3((TB_ * H_ / 4) / 256), dim3(256), 0, stream>>>(x, xb, TB_ * H_ / 4);
  cast_bf16<<<dim3((SB_ * H_ / 4) / 256), dim3(256), 0, stream>>>(mem, memb, SB_ * H_ / 4);

  // ---- weight transposes ----
  dim3 tb(32, 8);
  transpose_cast<<<dim3(H_ / 32, H_ / 32), tb, 0, stream>>>(Wq, WqT, H_, H_);
  transpose_cast<<<dim3(H_ / 32, H_ / 32), tb, 0, stream>>>(Wk, WkT, H_, H_);
  transpose_cast<<<dim3(H_ / 32, H_ / 32), tb, 0, stream>>>(Wv, WvT, H_, H_);
  transpose_cast<<<dim3(H_ / 32, H_ / 32), tb, 0, stream>>>(Wo, WoT, H_, H_);
  transpose_cast<<<dim3(F_ / 32, H_ / 32), tb, 0, stream>>>(W1, W1T, H_, F_);
  transpose_cast<<<dim3(H_ / 32, F_ / 32), tb, 0, stream>>>(W2, W2T, F_, H_);
  transpose_cast<<<dim3(4 * H_ / 32, 2 * H_ / 32), tb, 0, stream>>>(Wg, WgxT, 2 * H_, 4 * H_);
  transpose_cast<<<dim3(4 * H_ / 32, H_ / 32), tb, 0, stream>>>(Wg + (size_t)(2 * H_) * (4 * H_), WhT, H_, 4 * H_);
  rearrange_wh<<<dim3(2048), 256, 0, stream>>>(WhT, WhR);

  // ---- projections ----
  gemm_bt<<<dim3(H_ / 128, TB_ / 128), 256, 0, stream>>>(xb, WqT, qb, bq, H_, H_, 0.125f, 0);
  gemm_bt<<<dim3(H_ / 128, SB_ / 128), 256, 0, stream>>>(memb, WkT, kb, bk, H_, H_, 1.0f, 0);
  gemm_bt<<<dim3(H_ / 128, SB_ / 128), 256, 0, stream>>>(memb, WvT, vb, bv, H_, H_, 1.0f, 0);

  // ---- attention ----
  attn_kernel<<<dim3(B_ * NH_), 256, 0, stream>>>(qb, kb, vb, src_bias, ctxb);

  // ---- output proj -> xs[:, H:2H] ----
  gemm_bt<<<dim3(H_ / 128, TB_ / 128), 256, 0, stream>>>(ctxb, WoT, xs + H_, bo, H_, 2 * H_, 1.0f, 0);

  // ---- FFN -> xs[:, 0:H] ----
  gemm_bt<<<dim3(F_ / 128, TB_ / 128), 256, 0, stream>>>(xb, W1T, h1, b1, H_, F_, 1.0f, 1);
  gemm_bt<<<dim3(H_ / 128, TB_ / 128), 256, 0, stream>>>(h1, W2T, xs, b2, F_, 2 * H_, 1.0f, 0);

  // ---- gate x-part ----
  gemm_bt<<<dim3(4 * H_ / 128, TB_ / 128), 256, 0, stream>>>(xs, WgxT, gx, bg, 2 * H_, 4 * H_, 1.0f, 0);

  // ---- persistent LSTM (no barrier, no flags: stamped dataflow) ----
  lstm_persistent<<<dim3(64), 256, 0, stream>>>(gx, WhR, hseq, out);
}